// Round 1
// baseline (1114.128 us; speedup 1.0000x reference)
//
#include <hip/hip_runtime.h>

#define R_ 3
#define T_ 3
#define N_ 50000
#define OPS_ 24
#define E_ 400000
#define B_ 32
#define MAXDEG_ 8
#define QD_ 128
#define ED_ 128
#define H_ 128
#define G4_ (4*H_)   /* 512 */
#define HPAD 168     /* padded LDS h-row (bf16): 128 h + 25 one-hot + pad, 336 B */
#define PSLOTS 64    /* partial row-sum slots */
#define RB_ 96       /* 3 rounds x 32 batch */

typedef unsigned short u16;
typedef __attribute__((ext_vector_type(8))) short bf16x8;   // 8 bf16 = 4 VGPRs
typedef __attribute__((ext_vector_type(4))) float f32x4;

#define BF16_ONE ((short)0x3F80)

__device__ __forceinline__ short f2bf(float f){
  union { float f; unsigned u; } v; v.f = f;
  unsigned r = v.u + 0x7fffu + ((v.u >> 16) & 1u);
  return (short)(r >> 16);
}
__device__ __forceinline__ float bf2f(u16 u){
  union { unsigned u; float f; } v; v.u = ((unsigned)u) << 16; return v.f;
}
__device__ __forceinline__ float frcp(float x){ return __builtin_amdgcn_rcpf(x); }
__device__ __forceinline__ float fsig(float x){ return frcp(1.0f + __expf(-x)); }
// tanh(x) = 2*sigmoid(2x) - 1
__device__ __forceinline__ float ftanh(float x){
  return __builtin_fmaf(2.0f, fsig(2.0f * x), -1.0f);
}

// ---------------- query BiLSTM + attention: one block per (r,b) ----------------
__global__ void qattn_kernel(const int* __restrict__ queries, const float* __restrict__ qemb,
    const float* __restrict__ qWih, const float* __restrict__ qWhh,
    const float* __restrict__ qbih, const float* __restrict__ qbhh,
    const float* __restrict__ qlinW, const float* __restrict__ qlinb,
    float* __restrict__ query_attn /* R,T,B,25 */)
{
  int r = blockIdx.x / B_;
  int b = blockIdx.x % B_;
  int tid = threadIdx.x;   // 256
  __shared__ float x[QD_];
  __shared__ float gx[G4_];
  __shared__ float h[H_], c[H_];
  __shared__ float gtmp[G4_];
  __shared__ float hh[2][T_][H_];
  __shared__ float lg[OPS_ + 1];

  int q = queries[b];
  if (tid < QD_) x[tid] = qemb[q * QD_ + tid];
  __syncthreads();

  for (int dir = 0; dir < 2; ++dir){
    const float* Wih = qWih + (size_t)(r * 2 + dir) * G4_ * QD_;
    const float* Whh = qWhh + (size_t)(r * 2 + dir) * G4_ * H_;
    const float* bih = qbih + (r * 2 + dir) * G4_;
    const float* bhh = qbhh + (r * 2 + dir) * G4_;
    for (int j = tid; j < G4_; j += 256){
      const float4* wr = (const float4*)(Wih + (size_t)j * QD_);
      float s = bih[j] + bhh[j];
      for (int k = 0; k < QD_ / 4; ++k){
        float4 wv = wr[k];
        s += wv.x * x[4*k] + wv.y * x[4*k+1] + wv.z * x[4*k+2] + wv.w * x[4*k+3];
      }
      gx[j] = s;
    }
    if (tid < H_){ h[tid] = 0.f; c[tid] = 0.f; }
    __syncthreads();
    for (int t = 0; t < T_; ++t){
      for (int j = tid; j < G4_; j += 256){
        const float4* wr = (const float4*)(Whh + (size_t)j * H_);
        float s = 0.f;
        for (int k = 0; k < H_ / 4; ++k){
          float4 wv = wr[k];
          s += wv.x * h[4*k] + wv.y * h[4*k+1] + wv.z * h[4*k+2] + wv.w * h[4*k+3];
        }
        gtmp[j] = gx[j] + s;
      }
      __syncthreads();
      if (tid < H_){
        float gi = gtmp[tid], gf = gtmp[tid + H_], gg = gtmp[tid + 2*H_], go = gtmp[tid + 3*H_];
        float cn = fsig(gf) * c[tid] + fsig(gi) * ftanh(gg);
        float hn = fsig(go) * ftanh(cn);
        c[tid] = cn; h[tid] = hn;
        hh[dir][t][tid] = hn;
      }
      __syncthreads();
    }
  }

  for (int t = 0; t < T_; ++t){
    if (tid < OPS_ + 1){
      const float* wr = qlinW + tid * (2 * H_);
      float s = qlinb[tid];
      for (int k = 0; k < H_; ++k) s += wr[k] * hh[0][t][k];
      for (int k = 0; k < H_; ++k) s += wr[H_ + k] * hh[1][T_ - 1 - t][k];
      lg[tid] = s;
    }
    __syncthreads();
    if (tid == 0){
      float m = -1e30f;
      for (int o = 0; o < OPS_ + 1; ++o) m = fmaxf(m, lg[o]);
      float sum = 0.f;
      for (int o = 0; o < OPS_ + 1; ++o){ float e = __expf(lg[o] - m); lg[o] = e; sum += e; }
      float inv = frcp(sum);
      for (int o = 0; o < OPS_ + 1; ++o) lg[o] *= inv;
    }
    __syncthreads();
    if (tid < OPS_ + 1) query_attn[((size_t)(r * T_ + t) * B_ + b) * (OPS_ + 1) + tid] = lg[tid];
    __syncthreads();
  }
}

// ---- build B-operand buffers in MFMA-fragment order (eproj folded in) ----
__global__ void wbuild_kernel(const float* __restrict__ eWhh,
                              const float* __restrict__ eemb, const float* __restrict__ eWih,
                              const float* __restrict__ ebih, const float* __restrict__ ebhh,
                              u16* __restrict__ wtile, u16* __restrict__ wonehot)
{
  int idx = blockIdx.x * 256 + threadIdx.x;    // 2*32*5*64*8 = 163840
  if (idx >= 2 * 32 * 5 * 64 * 8) return;
  int jj = idx & 7;
  int lane = (idx >> 3) & 63;
  int kc = (idx >> 9) % 5;
  int gtile = (idx / (8 * 64 * 5)) & 31;
  int dir = idx / (8 * 64 * 5 * 32);
  int row = lane >> 4, col = lane & 15;
  int j = gtile * 16 + col;
  if (kc < 4){
    int k = kc * 32 + row * 8 + jj;
    float v = eWhh[((size_t)dir * G4_ + j) * H_ + k];
    wtile[((((size_t)dir * 32 + gtile) * 4 + kc) * 64 + lane) * 8 + jj] = (u16)f2bf(v);
  } else {
    int vdeg = row * 8 + jj;   // 0..31
    float v = 0.f;
    if (vdeg <= OPS_){
      const float4* wr = (const float4*)(eWih + (size_t)(dir * G4_ + j) * ED_);
      const float4* er = (const float4*)(eemb + (size_t)vdeg * ED_);
      float s = ebih[dir * G4_ + j] + ebhh[dir * G4_ + j];
      for (int k = 0; k < ED_ / 4; ++k){
        float4 wv = wr[k], ev = er[k];
        s += wv.x * ev.x + wv.y * ev.y + wv.z * ev.z + wv.w * ev.w;
      }
      v = s;
    }
    wonehot[(((size_t)dir * 32 + gtile) * 64 + lane) * 8 + jj] = (u16)f2bf(v);
  }
}

// ------ entity BiLSTM: 256 threads / 4 waves / 32 entities per block.
// Weights stream from global (L2-resident, 256 KB shared by all blocks) instead of a
// 128 KB LDS stage -> LDS drops to 21.5 KB -> 4-5 blocks/CU; hl double-buffered ->
// single barrier per timestep; independent blocks drift out of phase so MFMA of one
// overlaps activation VALU of another.
__global__ __launch_bounds__(256, 4) void elstm_kernel(
    const int* __restrict__ degs,
    const u16* __restrict__ wtile, const u16* __restrict__ wonehot,
    u16* __restrict__ houts /* 2,N,128 bf16 */)
{
  int tid = threadIdx.x;
  int lane = tid & 63;
  int wq = (tid >> 6) & 3;   // wave 0..3 owns gate-col unit {wq*2+(0,1), +8, +16, +24}
  int row = lane >> 4, col = lane & 15;
  int ebase = blockIdx.x * 32;

  __shared__ __align__(16) short hl[2][32 * HPAD];   // 2 x 10.5 KB ping-pong

  int eg0 = ebase + tid; if (eg0 >= N_) eg0 = N_ - 1;   // valid for tid<32 use

  for (int i = tid; i < 2 * 32 * HPAD; i += 256) ((short*)hl)[i] = 0;
  __syncthreads();
  if (tid < 32) hl[0][tid * HPAD + H_ + degs[(size_t)eg0 * MAXDEG_ + 0]] = BF16_ONE;
  __syncthreads();

  for (int dir = 0; dir < 2; ++dir){
    const u16* Wt  = wtile   + (size_t)dir * 32 * 4 * 64 * 8;
    const u16* Woh = wonehot + (size_t)dir * 32 * 64 * 8;
    float cst[16];
    #pragma unroll
    for (int i = 0; i < 16; ++i) cst[i] = 0.f;

    for (int t = 0; t < MAXDEG_; ++t){
      const short* hb = hl[t & 1];          // holds h_t (+ one-hot for step t)
      short*       hw = hl[(t + 1) & 1];    // receives h_{t+1}
      f32x4 acc[16];
      #pragma unroll
      for (int i = 0; i < 16; ++i) acc[i] = (f32x4){0.f, 0.f, 0.f, 0.f};

      #pragma unroll 1
      for (int kc = 0; kc < 4; ++kc){
        bf16x8 af0 = *(const bf16x8*)&hb[(col) * HPAD + kc * 32 + row * 8];
        bf16x8 af1 = *(const bf16x8*)&hb[(16 + col) * HPAD + kc * 32 + row * 8];
        #pragma unroll
        for (int g8 = 0; g8 < 8; ++g8){
          int gtile = (g8 >> 1) * 8 + wq * 2 + (g8 & 1);
          bf16x8 bfr = *(const bf16x8*)(Wt + (((size_t)gtile * 4 + kc) * 64 + lane) * 8);
          acc[g8 * 2 + 0] = __builtin_amdgcn_mfma_f32_16x16x32_bf16(af0, bfr, acc[g8 * 2 + 0], 0, 0, 0);
          acc[g8 * 2 + 1] = __builtin_amdgcn_mfma_f32_16x16x32_bf16(af1, bfr, acc[g8 * 2 + 1], 0, 0, 0);
        }
      }
      {
        bf16x8 af0 = *(const bf16x8*)&hb[(col) * HPAD + H_ + row * 8];
        bf16x8 af1 = *(const bf16x8*)&hb[(16 + col) * HPAD + H_ + row * 8];
        #pragma unroll
        for (int g8 = 0; g8 < 8; ++g8){
          int gtile = (g8 >> 1) * 8 + wq * 2 + (g8 & 1);
          bf16x8 bfr = *(const bf16x8*)(Woh + ((size_t)gtile * 64 + lane) * 8);
          acc[g8 * 2 + 0] = __builtin_amdgcn_mfma_f32_16x16x32_bf16(af0, bfr, acc[g8 * 2 + 0], 0, 0, 0);
          acc[g8 * 2 + 1] = __builtin_amdgcn_mfma_f32_16x16x32_bf16(af1, bfr, acc[g8 * 2 + 1], 0, 0, 0);
        }
      }

      // activation: reads only acc/cst, writes only hw -> no barrier needed before it.
      // fused-denominator LSTM cell: 5 exp + 3 rcp (vs 5 exp + 5 rcp).
      #pragma unroll
      for (int mt = 0; mt < 2; ++mt){
        #pragma unroll
        for (int reg = 0; reg < 4; ++reg){
          int e = mt * 16 + row * 4 + reg;
          #pragma unroll
          for (int gt2 = 0; gt2 < 2; ++gt2){
            int j = wq * 32 + gt2 * 16 + col;
            float gi = acc[(0 + gt2) * 2 + mt][reg];
            float gf = acc[(2 + gt2) * 2 + mt][reg];
            float gg = acc[(4 + gt2) * 2 + mt][reg];
            float go = acc[(6 + gt2) * 2 + mt][reg];
            int ci = (mt * 4 + reg) * 2 + gt2;
            float ef = __expf(-gf);
            float ea = __expf(-gi);
            float eb = __expf(-2.f * gg);
            float cn = cst[ci] * frcp(1.f + ef)
                     + (1.f - eb) * frcp((1.f + ea) * (1.f + eb));
            float eo = __expf(-go);
            float ed = __expf(-2.f * cn);
            float hn = (1.f - ed) * frcp((1.f + eo) * (1.f + ed));
            cst[ci] = cn;
            hw[e * HPAD + j] = f2bf(hn);
          }
        }
      }
      // one-hot maintenance on the write buffer: clear the slot set 2 steps ago,
      // set the slot step t+1 will read.
      if (tid < 32){
        const int* dr = degs + (size_t)eg0 * MAXDEG_;
        if (t >= 1)
          hw[tid * HPAD + H_ + dr[dir ? (MAXDEG_ - t) : (t - 1)]] = 0;
        if (t < MAXDEG_ - 1)
          hw[tid * HPAD + H_ + dr[dir ? (MAXDEG_ - 2 - t) : (t + 1)]] = BF16_ONE;
      }
      __syncthreads();
    }

    // MAXDEG_ even -> final h sits in hl[0]
    for (int i = tid; i < 32 * H_; i += 256){
      int e = i >> 7, k = i & 127;
      int n = ebase + e;
      if (n < N_) houts[(size_t)dir * N_ * H_ + (size_t)n * H_ + k] = (u16)hl[0][e * HPAD + k];
    }
    if (dir == 0){
      __syncthreads();
      for (int i = tid; i < 2 * 32 * HPAD; i += 256) ((short*)hl)[i] = 0;
      __syncthreads();
      if (tid < 32) hl[0][tid * HPAD + H_ + degs[(size_t)eg0 * MAXDEG_ + (MAXDEG_ - 1)]] = BF16_ONE;
      __syncthreads();
    }
  }
}

// ------------- entity attention: 10 entities x 24 ops per block, LDS-staged -------------
__global__ void eattn_kernel(const u16* __restrict__ hf, const u16* __restrict__ hb,
                             const float* __restrict__ elinW, const float* __restrict__ elinb,
                             float* __restrict__ attn /* N,24 */)
{
  __shared__ float W[OPS_][257];
  __shared__ float hhs[10][263];
  __shared__ float lgs[10][OPS_];
  int tid = threadIdx.x;    // 240
  int n0 = blockIdx.x * 10;
  for (int i = tid; i < OPS_ * 256; i += 240) W[i >> 8][i & 255] = elinW[i];
  for (int i = tid; i < 10 * H_; i += 240){
    int nl = i >> 7, k = i & 127;
    int n = n0 + nl;
    if (n < N_){
      hhs[nl][k]        = bf2f(hf[(size_t)n * H_ + k]);
      hhs[nl][H_ + k]   = bf2f(hb[(size_t)n * H_ + k]);
    }
  }
  __syncthreads();
  int nl = tid / OPS_;
  int o  = tid - nl * OPS_;
  int n  = n0 + nl;
  if (n < N_){
    float s = elinb[o];
    #pragma unroll 4
    for (int k = 0; k < 2 * H_; ++k) s += W[o][k] * hhs[nl][k];
    lgs[nl][o] = s;
  }
  __syncthreads();
  if (n < N_){
    float m = -1e30f;
    for (int i = 0; i < OPS_; ++i) m = fmaxf(m, lgs[nl][i]);
    float sum = 0.f;
    for (int i = 0; i < OPS_; ++i) sum += __expf(lgs[nl][i] - m);
    attn[(size_t)n * OPS_ + o] = __expf(lgs[nl][o] - m) * frcp(sum);
  }
}

// ---------------- CSR build: per-node in-edge AND out-edge lists ----------------
__global__ void csr_count_kernel(const int* __restrict__ theads, const int* __restrict__ ttails,
                                 int* __restrict__ counts)
{
  int e = blockIdx.x * 256 + threadIdx.x;
  if (e < E_){
    atomicAdd(&counts[ttails[e]], 1);
    atomicAdd(&counts[theads[e]], 1);
  }
}

__global__ void csr_scan_kernel(const int* __restrict__ counts, int* __restrict__ rowptr,
                                int* __restrict__ cursor, int* __restrict__ cursor2)
{
  __shared__ int lsum[1024];
  int t = threadIdx.x;
  const int CH = (N_ + 1023) / 1024;   // 49
  int base = t * CH;
  int s = 0;
  for (int i = 0; i < CH; ++i){
    int idx = base + i;
    if (idx < N_) s += counts[idx];
  }
  lsum[t] = s;
  __syncthreads();
  for (int o = 1; o < 1024; o <<= 1){
    int u = (t >= o) ? lsum[t - o] : 0;
    __syncthreads();
    lsum[t] += u;
    __syncthreads();
  }
  int run = lsum[t] - s;
  for (int i = 0; i < CH; ++i){
    int idx = base + i;
    if (idx < N_){
      rowptr[idx] = run;
      cursor[idx] = run;
      cursor2[idx] = run;
      run += counts[idx];
    }
  }
  if (t == 1023) rowptr[N_] = run;
}

__global__ void csr_fill_kernel(const int* __restrict__ rels, const int* __restrict__ theads,
                                const int* __restrict__ ttails, const float* __restrict__ attn,
                                int* __restrict__ cursor, int* __restrict__ cursor2,
                                uint2* __restrict__ ents, uint2* __restrict__ ents2)
{
  int e = blockIdx.x * 256 + threadIdx.x;
  if (e < E_){
    int hh = theads[e], tt = ttails[e], rel = rels[e];
    unsigned wb = __float_as_uint(attn[(size_t)hh * OPS_ + rel]);
    uint2 v1; v1.x = (unsigned)hh | ((unsigned)rel << 16);            v1.y = wb;
    uint2 v2; v2.x = (unsigned)tt | ((unsigned)(rel + OPS_/2) << 16); v2.y = wb;
    ents[atomicAdd(&cursor[tt], 1)] = v1;
    ents[atomicAdd(&cursor[hh], 1)] = v2;
    uint2 w1; w1.x = (unsigned)tt | ((unsigned)rel << 16);            w1.y = wb;
    uint2 w2; w2.x = (unsigned)hh | ((unsigned)(rel + OPS_/2) << 16); w2.y = wb;
    ents2[atomicAdd(&cursor2[hh], 1)] = w1;
    ents2[atomicAdd(&cursor2[tt], 1)] = w2;
  }
}

// ---- t=0 sparse step: u0 is one-hot(heads) -> u1 from out-edges of 32 head nodes ----
__global__ void t0_kernel(const int* __restrict__ heads, const float* __restrict__ query_attn,
                          const int* __restrict__ rowptr, const uint2* __restrict__ ents2,
                          float* __restrict__ u1 /* N x 96 */)
{
  int tid = threadIdx.x;
  if (tid >= RB_) return;
  int r = tid >> 5, b = tid & 31;
  const float* qa = query_attn + ((size_t)(r * T_ + 0) * B_ + b) * (OPS_ + 1);
  int hn = heads[b];
  int rb = r * 32 + b;
  u1[(size_t)hn * RB_ + rb] += qa[OPS_];
  int beg = rowptr[hn], end = rowptr[hn + 1];
  for (int i = beg; i < end; ++i){
    uint2 e = ents2[i];
    int dst = (int)(e.x & 0xFFFFu);
    int rl  = (int)(e.x >> 16);
    u1[(size_t)dst * RB_ + rb] += qa[rl] * __uint_as_float(e.y);
  }
}

// ---- t=1 dense self-term: u2 = qa1_24 (.) u1 (elementwise; replaces memset) ----
__global__ void u2init_kernel(const float* __restrict__ query_attn,
                              const float* __restrict__ u1, float* __restrict__ u2)
{
  __shared__ float q24[RB_];
  int tid = threadIdx.x;
  if (tid < RB_){
    int r = tid >> 5, b = tid & 31;
    q24[tid] = query_attn[((size_t)(r * T_ + 1) * B_ + b) * (OPS_ + 1) + OPS_];
  }
  __syncthreads();
  int idx = blockIdx.x * 256 + tid;
  if (idx < N_ * RB_) u2[idx] = u1[idx] * q24[idx % RB_];
}

// ---- t=1 sparse pushes: u1 nonzero only at {head} U outNbr(head) per column.
// Per-path 2-hop formulation; head's self-mass outflow is the single-hop term.
__global__ void t1push_kernel(const int* __restrict__ heads, const float* __restrict__ query_attn,
                              const int* __restrict__ rowptr, const uint2* __restrict__ ents2,
                              const float* __restrict__ u1, float* __restrict__ u2)
{
  __shared__ float qa0[OPS_ + 1], qa1[OPS_ + 1];
  int blk = blockIdx.x;   // 0..95
  int r = blk >> 5, b = blk & 31;
  int rb = r * 32 + b;
  int tid = threadIdx.x;  // 64
  if (tid < OPS_ + 1){
    qa0[tid] = query_attn[((size_t)(r * T_ + 0) * B_ + b) * (OPS_ + 1) + tid];
    qa1[tid] = query_attn[((size_t)(r * T_ + 1) * B_ + b) * (OPS_ + 1) + tid];
  }
  __syncthreads();
  int hd = heads[b];
  int beg = rowptr[hd], end = rowptr[hd + 1];
  float q024 = qa0[OPS_];
  for (int i = beg + tid; i < end; i += 64){
    uint2 e1 = ents2[i];
    int s  = (int)(e1.x & 0xFFFFu);
    int r1 = (int)(e1.x >> 16);
    float w1 = __uint_as_float(e1.y);
    atomicAdd(&u2[(size_t)s * RB_ + rb], qa1[r1] * w1 * q024);
    float v1 = qa0[r1] * w1;      // this path's share of u1[s]
    int b2 = rowptr[s], e2e = rowptr[s + 1];
    for (int jj = b2; jj < e2e; ++jj){
      uint2 e2 = ents2[jj];
      int d2 = (int)(e2.x & 0xFFFFu);
      int r2 = (int)(e2.x >> 16);
      atomicAdd(&u2[(size_t)d2 * RB_ + rb], qa1[r2] * __uint_as_float(e2.y) * v1);
    }
  }
}

// ---- batched dense gather (t=2): ONE WAVE per node, halves split 4-edge chunks ----
// 12 independent random u-loads + 4 ent loads in flight per half; halves combine
// via shfl_xor(32) -- same wave, same node (r14 bug: 8 nodes/block mixed waves).
__global__ __launch_bounds__(256) void gather3_kernel(
    const float* __restrict__ ucur, float* __restrict__ unxt,
    const float* __restrict__ query_attn, int t,
    const int* __restrict__ rowptr, const uint2* __restrict__ ents,
    float* __restrict__ partial /* PSLOTS x 96 */)
{
  __shared__ float qas[3 * B_ * (OPS_ + 1)];  // [r][b][o]
  __shared__ float red[RB_];
  int tid = threadIdx.x;
  for (int i = tid; i < 3 * B_ * (OPS_ + 1); i += 256){
    int r = i / (B_ * (OPS_ + 1));
    int rem = i - r * (B_ * (OPS_ + 1));
    qas[i] = query_attn[(size_t)(r * T_ + t) * B_ * (OPS_ + 1) + rem];
  }
  if (tid < RB_) red[tid] = 0.f;
  __syncthreads();
  int b  = tid & 31;
  int h  = (tid >> 5) & 1;              // half within wave
  int n = blockIdx.x * 4 + (tid >> 6);  // one wave per node; grid*4 == N_
  const float* q0 = &qas[0 * 800 + b * (OPS_ + 1)];
  const float* q1 = &qas[1 * 800 + b * (OPS_ + 1)];
  const float* q2 = &qas[2 * 800 + b * (OPS_ + 1)];
  size_t nb = (size_t)n * RB_;
  float a0 = 0.f, a1 = 0.f, a2 = 0.f;
  if (h == 0){
    a0 = ucur[nb + b]      * q0[OPS_];
    a1 = ucur[nb + 32 + b] * q1[OPS_];
    a2 = ucur[nb + 64 + b] * q2[OPS_];
  }
  int beg = rowptr[n], end = rowptr[n + 1];
  int cnt = end - beg;
  int nq = cnt >> 2;                 // full 4-edge chunks
  for (int c = h; c < nq; c += 2){
    int i0 = beg + 4 * c;
    uint2 e0 = ents[i0 + 0];
    uint2 e1 = ents[i0 + 1];
    uint2 e2 = ents[i0 + 2];
    uint2 e3 = ents[i0 + 3];
    size_t s0 = (size_t)(e0.x & 0xFFFFu) * RB_;
    size_t s1 = (size_t)(e1.x & 0xFFFFu) * RB_;
    size_t s2 = (size_t)(e2.x & 0xFFFFu) * RB_;
    size_t s3 = (size_t)(e3.x & 0xFFFFu) * RB_;
    float u00 = ucur[s0 + b], u01 = ucur[s0 + 32 + b], u02 = ucur[s0 + 64 + b];
    float u10 = ucur[s1 + b], u11 = ucur[s1 + 32 + b], u12 = ucur[s1 + 64 + b];
    float u20 = ucur[s2 + b], u21 = ucur[s2 + 32 + b], u22 = ucur[s2 + 64 + b];
    float u30 = ucur[s3 + b], u31 = ucur[s3 + 32 + b], u32 = ucur[s3 + 64 + b];
    int r0 = (int)(e0.x >> 16), r1 = (int)(e1.x >> 16);
    int r2 = (int)(e2.x >> 16), r3 = (int)(e3.x >> 16);
    float w0 = __uint_as_float(e0.y), w1 = __uint_as_float(e1.y);
    float w2 = __uint_as_float(e2.y), w3 = __uint_as_float(e3.y);
    a0 += q0[r0]*w0*u00 + q0[r1]*w1*u10 + q0[r2]*w2*u20 + q0[r3]*w3*u30;
    a1 += q1[r0]*w0*u01 + q1[r1]*w1*u11 + q1[r2]*w2*u21 + q1[r3]*w3*u31;
    a2 += q2[r0]*w0*u02 + q2[r1]*w1*u12 + q2[r2]*w2*u22 + q2[r3]*w3*u32;
  }
  if (h == 1){
    for (int i = beg + 4 * nq; i < end; ++i){
      uint2 e0 = ents[i];
      size_t s0 = (size_t)(e0.x & 0xFFFFu) * RB_;
      int r0 = (int)(e0.x >> 16);
      float w0 = __uint_as_float(e0.y);
      a0 += q0[r0] * w0 * ucur[s0 + b];
      a1 += q1[r0] * w0 * ucur[s0 + 32 + b];
      a2 += q2[r0] * w0 * ucur[s0 + 64 + b];
    }
  }
  a0 += __shfl_xor(a0, 32);
  a1 += __shfl_xor(a1, 32);
  a2 += __shfl_xor(a2, 32);
  if (h == 0){
    unxt[nb + b]      = a0;
    unxt[nb + 32 + b] = a1;
    unxt[nb + 64 + b] = a2;
    atomicAdd(&red[b], a0);
    atomicAdd(&red[32 + b], a1);
    atomicAdd(&red[64 + b], a2);
  }
  __syncthreads();
  if (tid < RB_)
    atomicAdd(&partial[(blockIdx.x & (PSLOTS - 1)) * RB_ + tid], red[tid]);
}

// ---- finalize + transpose: out[b][n] = sum_r u[n][r*32+b] / rowsum_r ----
__global__ void fintrans_kernel(const float* __restrict__ u, const float* __restrict__ partial,
                                float* __restrict__ out)
{
  __shared__ float sinv[RB_];
  __shared__ float t[B_][72];
  int tid = threadIdx.x;   // 256
  if (tid < RB_){
    float s = 0.f;
    #pragma unroll 8
    for (int k = 0; k < PSLOTS; ++k) s += partial[k * RB_ + tid];
    sinv[tid] = frcp(fmaxf(1e-20f, s));
  }
  __syncthreads();
  int n0 = blockIdx.x * 64;
  for (int i = tid; i < 64 * B_; i += 256){
    int nl = i >> 5, b = i & 31;
    int n = n0 + nl;
    float v = 0.f;
    if (n < N_){
      size_t nb = (size_t)n * RB_;
      v = u[nb + b] * sinv[b] + u[nb + 32 + b] * sinv[32 + b] + u[nb + 64 + b] * sinv[64 + b];
    }
    t[b][nl] = v;
  }
  __syncthreads();
  for (int i = tid; i < 64 * B_; i += 256){
    int b = i >> 6, nl = i & 63;
    int n = n0 + nl;
    if (n < N_) out[(size_t)b * N_ + n] = t[b][nl];
  }
}

extern "C" void kernel_launch(void* const* d_in, const int* in_sizes, int n_in,
                              void* d_out, int out_size, void* d_ws, size_t ws_size,
                              hipStream_t stream)
{
  const int*   queries = (const int*)d_in[0];
  const int*   heads   = (const int*)d_in[1];
  const int*   rels    = (const int*)d_in[2];
  const int*   t_heads = (const int*)d_in[3];
  const int*   t_tails = (const int*)d_in[4];
  const int*   edeg    = (const int*)d_in[5];
  const float* qemb    = (const float*)d_in[6];
  const float* eemb    = (const float*)d_in[7];
  const float* qWih    = (const float*)d_in[8];
  const float* qWhh    = (const float*)d_in[9];
  const float* qbih    = (const float*)d_in[10];
  const float* qbhh    = (const float*)d_in[11];
  const float* eWih    = (const float*)d_in[12];
  const float* eWhh    = (const float*)d_in[13];
  const float* ebih    = (const float*)d_in[14];
  const float* ebhh    = (const float*)d_in[15];
  const float* qlinW   = (const float*)d_in[16];
  const float* qlinb   = (const float*)d_in[17];
  const float* elinW   = (const float*)d_in[18];
  const float* elinb   = (const float*)d_in[19];
  float* out = (float*)d_out;

  char* ws = (char*)d_ws;
  size_t off = 0;
  auto alloc = [&](size_t bytes){ void* p = ws + off; off += (bytes + 255) & ~(size_t)255; return p; };
  // bigA (25.6 MB): houts during [elstm, eattn]; after eattn dead ->
  //   ents (6.4 MB, csr_fill) at +0, u2 (19.2 MB) at +6.4 MB.
  char*  bigA  = (char*)alloc((size_t)2 * N_ * H_ * 2);               // 25,600,000
  u16*   houts = (u16*)bigA;
  uint2* ents  = (uint2*)bigA;                                        // in-CSR, 6.4 MB
  float* u2    = (float*)(bigA + (size_t)2 * E_ * 8);                 // 19.2 MB
  // bigB (19.2 MB): attn (4.8 MB) during [eattn, csr_fill]; then u1; then u3.
  char*  bigB  = (char*)alloc((size_t)N_ * RB_ * 4);
  float* attn  = (float*)bigB;
  float* u1    = (float*)bigB;
  float* u3    = (float*)bigB;
  uint2* ents2      = (uint2*)alloc((size_t)2 * E_ * 8);              // out-CSR, 6.4 MB
  float* query_attn = (float*)alloc((size_t)R_ * T_ * B_ * (OPS_ + 1) * 4);
  u16*   wtile      = (u16*)  alloc((size_t)2 * 32 * 4 * 64 * 8 * 2);
  u16*   wonehot    = (u16*)  alloc((size_t)2 * 32 * 64 * 8 * 2);
  int*   counts     = (int*)  alloc((size_t)(N_ + 1) * 4);
  int*   rowptr     = (int*)  alloc((size_t)(N_ + 1) * 4);
  int*   cursor     = (int*)  alloc((size_t)(N_ + 1) * 4);
  int*   cursor2    = (int*)  alloc((size_t)(N_ + 1) * 4);
  float* sumsP      = (float*)alloc((size_t)PSLOTS * RB_ * 4);        // t2 partials only
  // total ~52 MB

  hipMemsetAsync(sumsP, 0, (size_t)PSLOTS * RB_ * 4, stream);
  hipMemsetAsync(counts, 0, (size_t)(N_ + 1) * 4, stream);

  qattn_kernel<<<R_ * B_, 256, 0, stream>>>(queries, qemb, qWih, qWhh, qbih, qbhh,
                                            qlinW, qlinb, query_attn);
  wbuild_kernel<<<(2 * 32 * 5 * 64 * 8 + 255) / 256, 256, 0, stream>>>(
      eWhh, eemb, eWih, ebih, ebhh, wtile, wonehot);
  csr_count_kernel<<<(E_ + 255) / 256, 256, 0, stream>>>(t_heads, t_tails, counts);
  csr_scan_kernel<<<1, 1024, 0, stream>>>(counts, rowptr, cursor, cursor2);
  elstm_kernel<<<(N_ + 31) / 32, 256, 0, stream>>>(edeg, wtile, wonehot, houts);
  eattn_kernel<<<(N_ + 9) / 10, 240, 0, stream>>>(houts, houts + (size_t)N_ * H_,
                                                  elinW, elinb, attn);
  // houts dead -> ents may take bigA[0:6.4M]; attn still live (read by csr_fill):
  csr_fill_kernel<<<(E_ + 255) / 256, 256, 0, stream>>>(rels, t_heads, t_tails, attn,
                                                        cursor, cursor2, ents, ents2);
  // attn dead -> u1 takes bigB
  hipMemsetAsync(u1, 0, (size_t)N_ * RB_ * 4, stream);
  t0_kernel<<<1, 128, 0, stream>>>(heads, query_attn, rowptr, ents2, u1);
  // t=1: dense self-term + sparse 2-hop pushes (replaces a full dense gather)
  u2init_kernel<<<(N_ * RB_ + 255) / 256, 256, 0, stream>>>(query_attn, u1, u2);
  t1push_kernel<<<RB_, 64, 0, stream>>>(heads, query_attn, rowptr, ents2, u1, u2);
  // t=2: dense gather (u1 dead; u3 overwrites bigB)
  gather3_kernel<<<N_ / 4, 256, 0, stream>>>(u2, u3, query_attn, 2, rowptr, ents, sumsP);
  fintrans_kernel<<<(N_ + 63) / 64, 256, 0, stream>>>(u3, sumsP, out);
}

// Round 2
// 882.956 us; speedup vs baseline: 1.2618x; 1.2618x over previous
//
#include <hip/hip_runtime.h>

#define R_ 3
#define T_ 3
#define N_ 50000
#define OPS_ 24
#define E_ 400000
#define B_ 32
#define MAXDEG_ 8
#define QD_ 128
#define ED_ 128
#define H_ 128
#define G4_ (4*H_)   /* 512 */
#define HPAD 168     /* padded LDS h-row (bf16): 128 h + 25 one-hot + pad, 336 B */
#define PSLOTS 64    /* partial row-sum slots */
#define RB_ 96       /* 3 rounds x 32 batch */

typedef unsigned short u16;
typedef __attribute__((ext_vector_type(8))) short bf16x8;   // 8 bf16 = 4 VGPRs
typedef __attribute__((ext_vector_type(4))) float f32x4;

#define BF16_ONE ((short)0x3F80)

__device__ __forceinline__ short f2bf(float f){
  union { float f; unsigned u; } v; v.f = f;
  unsigned r = v.u + 0x7fffu + ((v.u >> 16) & 1u);
  return (short)(r >> 16);
}
__device__ __forceinline__ float bf2f(u16 u){
  union { unsigned u; float f; } v; v.u = ((unsigned)u) << 16; return v.f;
}
__device__ __forceinline__ float frcp(float x){ return __builtin_amdgcn_rcpf(x); }
__device__ __forceinline__ float fsig(float x){ return frcp(1.0f + __expf(-x)); }
// tanh(x) = 2*sigmoid(2x) - 1
__device__ __forceinline__ float ftanh(float x){
  return __builtin_fmaf(2.0f, fsig(2.0f * x), -1.0f);
}

// ---------------- query BiLSTM + attention: one block per (r,b) ----------------
__global__ void qattn_kernel(const int* __restrict__ queries, const float* __restrict__ qemb,
    const float* __restrict__ qWih, const float* __restrict__ qWhh,
    const float* __restrict__ qbih, const float* __restrict__ qbhh,
    const float* __restrict__ qlinW, const float* __restrict__ qlinb,
    float* __restrict__ query_attn /* R,T,B,25 */)
{
  int r = blockIdx.x / B_;
  int b = blockIdx.x % B_;
  int tid = threadIdx.x;   // 256
  __shared__ float x[QD_];
  __shared__ float gx[G4_];
  __shared__ float h[H_], c[H_];
  __shared__ float gtmp[G4_];
  __shared__ float hh[2][T_][H_];
  __shared__ float lg[OPS_ + 1];

  int q = queries[b];
  if (tid < QD_) x[tid] = qemb[q * QD_ + tid];
  __syncthreads();

  for (int dir = 0; dir < 2; ++dir){
    const float* Wih = qWih + (size_t)(r * 2 + dir) * G4_ * QD_;
    const float* Whh = qWhh + (size_t)(r * 2 + dir) * G4_ * H_;
    const float* bih = qbih + (r * 2 + dir) * G4_;
    const float* bhh = qbhh + (r * 2 + dir) * G4_;
    for (int j = tid; j < G4_; j += 256){
      const float4* wr = (const float4*)(Wih + (size_t)j * QD_);
      float s = bih[j] + bhh[j];
      for (int k = 0; k < QD_ / 4; ++k){
        float4 wv = wr[k];
        s += wv.x * x[4*k] + wv.y * x[4*k+1] + wv.z * x[4*k+2] + wv.w * x[4*k+3];
      }
      gx[j] = s;
    }
    if (tid < H_){ h[tid] = 0.f; c[tid] = 0.f; }
    __syncthreads();
    for (int t = 0; t < T_; ++t){
      for (int j = tid; j < G4_; j += 256){
        const float4* wr = (const float4*)(Whh + (size_t)j * H_);
        float s = 0.f;
        for (int k = 0; k < H_ / 4; ++k){
          float4 wv = wr[k];
          s += wv.x * h[4*k] + wv.y * h[4*k+1] + wv.z * h[4*k+2] + wv.w * h[4*k+3];
        }
        gtmp[j] = gx[j] + s;
      }
      __syncthreads();
      if (tid < H_){
        float gi = gtmp[tid], gf = gtmp[tid + H_], gg = gtmp[tid + 2*H_], go = gtmp[tid + 3*H_];
        float cn = fsig(gf) * c[tid] + fsig(gi) * ftanh(gg);
        float hn = fsig(go) * ftanh(cn);
        c[tid] = cn; h[tid] = hn;
        hh[dir][t][tid] = hn;
      }
      __syncthreads();
    }
  }

  for (int t = 0; t < T_; ++t){
    if (tid < OPS_ + 1){
      const float* wr = qlinW + tid * (2 * H_);
      float s = qlinb[tid];
      for (int k = 0; k < H_; ++k) s += wr[k] * hh[0][t][k];
      for (int k = 0; k < H_; ++k) s += wr[H_ + k] * hh[1][T_ - 1 - t][k];
      lg[tid] = s;
    }
    __syncthreads();
    if (tid == 0){
      float m = -1e30f;
      for (int o = 0; o < OPS_ + 1; ++o) m = fmaxf(m, lg[o]);
      float sum = 0.f;
      for (int o = 0; o < OPS_ + 1; ++o){ float e = __expf(lg[o] - m); lg[o] = e; sum += e; }
      float inv = frcp(sum);
      for (int o = 0; o < OPS_ + 1; ++o) lg[o] *= inv;
    }
    __syncthreads();
    if (tid < OPS_ + 1) query_attn[((size_t)(r * T_ + t) * B_ + b) * (OPS_ + 1) + tid] = lg[tid];
    __syncthreads();
  }
}

// ---- build B-operand buffers in MFMA-fragment order (eproj folded in) ----
__global__ void wbuild_kernel(const float* __restrict__ eWhh,
                              const float* __restrict__ eemb, const float* __restrict__ eWih,
                              const float* __restrict__ ebih, const float* __restrict__ ebhh,
                              u16* __restrict__ wtile, u16* __restrict__ wonehot)
{
  int idx = blockIdx.x * 256 + threadIdx.x;    // 2*32*5*64*8 = 163840
  if (idx >= 2 * 32 * 5 * 64 * 8) return;
  int jj = idx & 7;
  int lane = (idx >> 3) & 63;
  int kc = (idx >> 9) % 5;
  int gtile = (idx / (8 * 64 * 5)) & 31;
  int dir = idx / (8 * 64 * 5 * 32);
  int row = lane >> 4, col = lane & 15;
  int j = gtile * 16 + col;
  if (kc < 4){
    int k = kc * 32 + row * 8 + jj;
    float v = eWhh[((size_t)dir * G4_ + j) * H_ + k];
    wtile[((((size_t)dir * 32 + gtile) * 4 + kc) * 64 + lane) * 8 + jj] = (u16)f2bf(v);
  } else {
    int vdeg = row * 8 + jj;   // 0..31
    float v = 0.f;
    if (vdeg <= OPS_){
      const float4* wr = (const float4*)(eWih + (size_t)(dir * G4_ + j) * ED_);
      const float4* er = (const float4*)(eemb + (size_t)vdeg * ED_);
      float s = ebih[dir * G4_ + j] + ebhh[dir * G4_ + j];
      for (int k = 0; k < ED_ / 4; ++k){
        float4 wv = wr[k], ev = er[k];
        s += wv.x * ev.x + wv.y * ev.y + wv.z * ev.z + wv.w * ev.w;
      }
      v = s;
    }
    wonehot[(((size_t)dir * 32 + gtile) * 64 + lane) * 8 + jj] = (u16)f2bf(v);
  }
}

// ------ entity BiLSTM: 512 threads / 8 waves / 32 entities per block.
// Weights stream from global (288 KB total, L2-resident) -> no LDS weight stage.
// Each wave owns h-cols [w*16,w*16+16) and all 4 gate types for that slice:
// acc = 8 f32x4 (32 regs) + cst[8] + frags -> ~100 total regs, fits the 128-reg
// cap of launch_bounds(512,4) WITHOUT spilling (round-1 failure mode: 256-thr
// decomposition needed 64 acc + 80 arch = spill -> 0.93 GB scratch traffic).
// hl double-buffered -> single barrier per timestep.
__global__ __launch_bounds__(512, 4) void elstm_kernel(
    const int* __restrict__ degs,
    const u16* __restrict__ wtile, const u16* __restrict__ wonehot,
    u16* __restrict__ houts /* 2,N,128 bf16 */)
{
  int tid = threadIdx.x;
  int lane = tid & 63;
  int w = tid >> 6;          // wave 0..7
  int row = lane >> 4, col = lane & 15;
  int ebase = blockIdx.x * 32;

  __shared__ __align__(16) short hl[2][32 * HPAD];   // 2 x 10.5 KB ping-pong

  int eg0 = ebase + tid; if (eg0 >= N_) eg0 = N_ - 1;   // valid for tid<32 use

  for (int i = tid; i < 2 * 32 * HPAD; i += 512) ((short*)hl)[i] = 0;
  __syncthreads();
  if (tid < 32) hl[0][tid * HPAD + H_ + degs[(size_t)eg0 * MAXDEG_ + 0]] = BF16_ONE;
  __syncthreads();

  for (int dir = 0; dir < 2; ++dir){
    const u16* Wt  = wtile   + (size_t)dir * 32 * 4 * 64 * 8;
    const u16* Woh = wonehot + (size_t)dir * 32 * 64 * 8;
    float cst[8];
    #pragma unroll
    for (int i = 0; i < 8; ++i) cst[i] = 0.f;

    for (int t = 0; t < MAXDEG_; ++t){
      const short* hb = hl[t & 1];          // holds h_t (+ one-hot for step t)
      short*       hw = hl[(t + 1) & 1];    // receives h_{t+1}
      f32x4 acc[8];
      #pragma unroll
      for (int i = 0; i < 8; ++i) acc[i] = (f32x4){0.f, 0.f, 0.f, 0.f};

      #pragma unroll 1
      for (int kc = 0; kc < 4; ++kc){
        bf16x8 af0 = *(const bf16x8*)&hb[(col) * HPAD + kc * 32 + row * 8];
        bf16x8 af1 = *(const bf16x8*)&hb[(16 + col) * HPAD + kc * 32 + row * 8];
        #pragma unroll
        for (int g = 0; g < 4; ++g){   // gate type; gtile = g*8 + w
          bf16x8 bfr = *(const bf16x8*)(Wt + ((((size_t)(g * 8 + w)) * 4 + kc) * 64 + lane) * 8);
          acc[g * 2 + 0] = __builtin_amdgcn_mfma_f32_16x16x32_bf16(af0, bfr, acc[g * 2 + 0], 0, 0, 0);
          acc[g * 2 + 1] = __builtin_amdgcn_mfma_f32_16x16x32_bf16(af1, bfr, acc[g * 2 + 1], 0, 0, 0);
        }
      }
      {
        bf16x8 af0 = *(const bf16x8*)&hb[(col) * HPAD + H_ + row * 8];
        bf16x8 af1 = *(const bf16x8*)&hb[(16 + col) * HPAD + H_ + row * 8];
        #pragma unroll
        for (int g = 0; g < 4; ++g){
          bf16x8 bfr = *(const bf16x8*)(Woh + (((size_t)(g * 8 + w)) * 64 + lane) * 8);
          acc[g * 2 + 0] = __builtin_amdgcn_mfma_f32_16x16x32_bf16(af0, bfr, acc[g * 2 + 0], 0, 0, 0);
          acc[g * 2 + 1] = __builtin_amdgcn_mfma_f32_16x16x32_bf16(af1, bfr, acc[g * 2 + 1], 0, 0, 0);
        }
      }

      // activation: reads only acc/cst, writes only hw -> no barrier needed before it.
      // fused-denominator LSTM cell: 5 exp + 3 rcp.
      #pragma unroll
      for (int mt = 0; mt < 2; ++mt){
        #pragma unroll
        for (int reg = 0; reg < 4; ++reg){
          int e = mt * 16 + row * 4 + reg;
          int j = w * 16 + col;
          float gi = acc[0 + mt][reg];
          float gf = acc[2 + mt][reg];
          float gg = acc[4 + mt][reg];
          float go = acc[6 + mt][reg];
          int ci = mt * 4 + reg;
          float ef = __expf(-gf);
          float ea = __expf(-gi);
          float eb = __expf(-2.f * gg);
          float cn = cst[ci] * frcp(1.f + ef)
                   + (1.f - eb) * frcp((1.f + ea) * (1.f + eb));
          float eo = __expf(-go);
          float ed = __expf(-2.f * cn);
          float hn = (1.f - ed) * frcp((1.f + eo) * (1.f + ed));
          cst[ci] = cn;
          hw[e * HPAD + j] = f2bf(hn);
        }
      }
      // one-hot maintenance on the write buffer: clear the slot set 2 steps ago,
      // set the slot step t+1 will read (clear BEFORE set handles repeated degrees).
      if (tid < 32){
        const int* dr = degs + (size_t)eg0 * MAXDEG_;
        if (t >= 1)
          hw[tid * HPAD + H_ + dr[dir ? (MAXDEG_ - t) : (t - 1)]] = 0;
        if (t < MAXDEG_ - 1)
          hw[tid * HPAD + H_ + dr[dir ? (MAXDEG_ - 2 - t) : (t + 1)]] = BF16_ONE;
      }
      __syncthreads();
    }

    // MAXDEG_ even -> final h sits in hl[0]
    for (int i = tid; i < 32 * H_; i += 512){
      int e = i >> 7, k = i & 127;
      int n = ebase + e;
      if (n < N_) houts[(size_t)dir * N_ * H_ + (size_t)n * H_ + k] = (u16)hl[0][e * HPAD + k];
    }
    if (dir == 0){
      __syncthreads();
      for (int i = tid; i < 2 * 32 * HPAD; i += 512) ((short*)hl)[i] = 0;
      __syncthreads();
      if (tid < 32) hl[0][tid * HPAD + H_ + degs[(size_t)eg0 * MAXDEG_ + (MAXDEG_ - 1)]] = BF16_ONE;
      __syncthreads();
    }
  }
}

// ------------- entity attention: 10 entities x 24 ops per block, LDS-staged -------------
__global__ void eattn_kernel(const u16* __restrict__ hf, const u16* __restrict__ hb,
                             const float* __restrict__ elinW, const float* __restrict__ elinb,
                             float* __restrict__ attn /* N,24 */)
{
  __shared__ float W[OPS_][257];
  __shared__ float hhs[10][263];
  __shared__ float lgs[10][OPS_];
  int tid = threadIdx.x;    // 240
  int n0 = blockIdx.x * 10;
  for (int i = tid; i < OPS_ * 256; i += 240) W[i >> 8][i & 255] = elinW[i];
  for (int i = tid; i < 10 * H_; i += 240){
    int nl = i >> 7, k = i & 127;
    int n = n0 + nl;
    if (n < N_){
      hhs[nl][k]        = bf2f(hf[(size_t)n * H_ + k]);
      hhs[nl][H_ + k]   = bf2f(hb[(size_t)n * H_ + k]);
    }
  }
  __syncthreads();
  int nl = tid / OPS_;
  int o  = tid - nl * OPS_;
  int n  = n0 + nl;
  if (n < N_){
    float s = elinb[o];
    #pragma unroll 4
    for (int k = 0; k < 2 * H_; ++k) s += W[o][k] * hhs[nl][k];
    lgs[nl][o] = s;
  }
  __syncthreads();
  if (n < N_){
    float m = -1e30f;
    for (int i = 0; i < OPS_; ++i) m = fmaxf(m, lgs[nl][i]);
    float sum = 0.f;
    for (int i = 0; i < OPS_; ++i) sum += __expf(lgs[nl][i] - m);
    attn[(size_t)n * OPS_ + o] = __expf(lgs[nl][o] - m) * frcp(sum);
  }
}

// ---------------- CSR build: per-node in-edge AND out-edge lists ----------------
__global__ void csr_count_kernel(const int* __restrict__ theads, const int* __restrict__ ttails,
                                 int* __restrict__ counts)
{
  int e = blockIdx.x * 256 + threadIdx.x;
  if (e < E_){
    atomicAdd(&counts[ttails[e]], 1);
    atomicAdd(&counts[theads[e]], 1);
  }
}

__global__ void csr_scan_kernel(const int* __restrict__ counts, int* __restrict__ rowptr,
                                int* __restrict__ cursor, int* __restrict__ cursor2)
{
  __shared__ int lsum[1024];
  int t = threadIdx.x;
  const int CH = (N_ + 1023) / 1024;   // 49
  int base = t * CH;
  int s = 0;
  for (int i = 0; i < CH; ++i){
    int idx = base + i;
    if (idx < N_) s += counts[idx];
  }
  lsum[t] = s;
  __syncthreads();
  for (int o = 1; o < 1024; o <<= 1){
    int u = (t >= o) ? lsum[t - o] : 0;
    __syncthreads();
    lsum[t] += u;
    __syncthreads();
  }
  int run = lsum[t] - s;
  for (int i = 0; i < CH; ++i){
    int idx = base + i;
    if (idx < N_){
      rowptr[idx] = run;
      cursor[idx] = run;
      cursor2[idx] = run;
      run += counts[idx];
    }
  }
  if (t == 1023) rowptr[N_] = run;
}

__global__ void csr_fill_kernel(const int* __restrict__ rels, const int* __restrict__ theads,
                                const int* __restrict__ ttails, const float* __restrict__ attn,
                                int* __restrict__ cursor, int* __restrict__ cursor2,
                                uint2* __restrict__ ents, uint2* __restrict__ ents2)
{
  int e = blockIdx.x * 256 + threadIdx.x;
  if (e < E_){
    int hh = theads[e], tt = ttails[e], rel = rels[e];
    unsigned wb = __float_as_uint(attn[(size_t)hh * OPS_ + rel]);
    uint2 v1; v1.x = (unsigned)hh | ((unsigned)rel << 16);            v1.y = wb;
    uint2 v2; v2.x = (unsigned)tt | ((unsigned)(rel + OPS_/2) << 16); v2.y = wb;
    ents[atomicAdd(&cursor[tt], 1)] = v1;
    ents[atomicAdd(&cursor[hh], 1)] = v2;
    uint2 w1; w1.x = (unsigned)tt | ((unsigned)rel << 16);            w1.y = wb;
    uint2 w2; w2.x = (unsigned)hh | ((unsigned)(rel + OPS_/2) << 16); w2.y = wb;
    ents2[atomicAdd(&cursor2[hh], 1)] = w1;
    ents2[atomicAdd(&cursor2[tt], 1)] = w2;
  }
}

// ---- t=0 sparse step: u0 is one-hot(heads) -> u1 from out-edges of 32 head nodes ----
__global__ void t0_kernel(const int* __restrict__ heads, const float* __restrict__ query_attn,
                          const int* __restrict__ rowptr, const uint2* __restrict__ ents2,
                          float* __restrict__ u1 /* N x 96 */)
{
  int tid = threadIdx.x;
  if (tid >= RB_) return;
  int r = tid >> 5, b = tid & 31;
  const float* qa = query_attn + ((size_t)(r * T_ + 0) * B_ + b) * (OPS_ + 1);
  int hn = heads[b];
  int rb = r * 32 + b;
  u1[(size_t)hn * RB_ + rb] += qa[OPS_];
  int beg = rowptr[hn], end = rowptr[hn + 1];
  for (int i = beg; i < end; ++i){
    uint2 e = ents2[i];
    int dst = (int)(e.x & 0xFFFFu);
    int rl  = (int)(e.x >> 16);
    u1[(size_t)dst * RB_ + rb] += qa[rl] * __uint_as_float(e.y);
  }
}

// ---- t=1 dense self-term: u2 = qa1_24 (.) u1 (elementwise; replaces memset) ----
__global__ void u2init_kernel(const float* __restrict__ query_attn,
                              const float* __restrict__ u1, float* __restrict__ u2)
{
  __shared__ float q24[RB_];
  int tid = threadIdx.x;
  if (tid < RB_){
    int r = tid >> 5, b = tid & 31;
    q24[tid] = query_attn[((size_t)(r * T_ + 1) * B_ + b) * (OPS_ + 1) + OPS_];
  }
  __syncthreads();
  int idx = blockIdx.x * 256 + tid;
  if (idx < N_ * RB_) u2[idx] = u1[idx] * q24[idx % RB_];
}

// ---- t=1 sparse pushes: u1 nonzero only at {head} U outNbr(head) per column.
// Per-path 2-hop formulation; head's self-mass outflow is the single-hop term.
__global__ void t1push_kernel(const int* __restrict__ heads, const float* __restrict__ query_attn,
                              const int* __restrict__ rowptr, const uint2* __restrict__ ents2,
                              const float* __restrict__ u1, float* __restrict__ u2)
{
  __shared__ float qa0[OPS_ + 1], qa1[OPS_ + 1];
  int blk = blockIdx.x;   // 0..95
  int r = blk >> 5, b = blk & 31;
  int rb = r * 32 + b;
  int tid = threadIdx.x;  // 64
  if (tid < OPS_ + 1){
    qa0[tid] = query_attn[((size_t)(r * T_ + 0) * B_ + b) * (OPS_ + 1) + tid];
    qa1[tid] = query_attn[((size_t)(r * T_ + 1) * B_ + b) * (OPS_ + 1) + tid];
  }
  __syncthreads();
  int hd = heads[b];
  int beg = rowptr[hd], end = rowptr[hd + 1];
  float q024 = qa0[OPS_];
  for (int i = beg + tid; i < end; i += 64){
    uint2 e1 = ents2[i];
    int s  = (int)(e1.x & 0xFFFFu);
    int r1 = (int)(e1.x >> 16);
    float w1 = __uint_as_float(e1.y);
    atomicAdd(&u2[(size_t)s * RB_ + rb], qa1[r1] * w1 * q024);
    float v1 = qa0[r1] * w1;      // this path's share of u1[s]
    int b2 = rowptr[s], e2e = rowptr[s + 1];
    for (int jj = b2; jj < e2e; ++jj){
      uint2 e2 = ents2[jj];
      int d2 = (int)(e2.x & 0xFFFFu);
      int r2 = (int)(e2.x >> 16);
      atomicAdd(&u2[(size_t)d2 * RB_ + rb], qa1[r2] * __uint_as_float(e2.y) * v1);
    }
  }
}

// ---- batched dense gather (t=2): ONE WAVE per node, halves split 4-edge chunks ----
__global__ __launch_bounds__(256) void gather3_kernel(
    const float* __restrict__ ucur, float* __restrict__ unxt,
    const float* __restrict__ query_attn, int t,
    const int* __restrict__ rowptr, const uint2* __restrict__ ents,
    float* __restrict__ partial /* PSLOTS x 96 */)
{
  __shared__ float qas[3 * B_ * (OPS_ + 1)];  // [r][b][o]
  __shared__ float red[RB_];
  int tid = threadIdx.x;
  for (int i = tid; i < 3 * B_ * (OPS_ + 1); i += 256){
    int r = i / (B_ * (OPS_ + 1));
    int rem = i - r * (B_ * (OPS_ + 1));
    qas[i] = query_attn[(size_t)(r * T_ + t) * B_ * (OPS_ + 1) + rem];
  }
  if (tid < RB_) red[tid] = 0.f;
  __syncthreads();
  int b  = tid & 31;
  int h  = (tid >> 5) & 1;              // half within wave
  int n = blockIdx.x * 4 + (tid >> 6);  // one wave per node; grid*4 == N_
  const float* q0 = &qas[0 * 800 + b * (OPS_ + 1)];
  const float* q1 = &qas[1 * 800 + b * (OPS_ + 1)];
  const float* q2 = &qas[2 * 800 + b * (OPS_ + 1)];
  size_t nb = (size_t)n * RB_;
  float a0 = 0.f, a1 = 0.f, a2 = 0.f;
  if (h == 0){
    a0 = ucur[nb + b]      * q0[OPS_];
    a1 = ucur[nb + 32 + b] * q1[OPS_];
    a2 = ucur[nb + 64 + b] * q2[OPS_];
  }
  int beg = rowptr[n], end = rowptr[n + 1];
  int cnt = end - beg;
  int nq = cnt >> 2;                 // full 4-edge chunks
  for (int c = h; c < nq; c += 2){
    int i0 = beg + 4 * c;
    uint2 e0 = ents[i0 + 0];
    uint2 e1 = ents[i0 + 1];
    uint2 e2 = ents[i0 + 2];
    uint2 e3 = ents[i0 + 3];
    size_t s0 = (size_t)(e0.x & 0xFFFFu) * RB_;
    size_t s1 = (size_t)(e1.x & 0xFFFFu) * RB_;
    size_t s2 = (size_t)(e2.x & 0xFFFFu) * RB_;
    size_t s3 = (size_t)(e3.x & 0xFFFFu) * RB_;
    float u00 = ucur[s0 + b], u01 = ucur[s0 + 32 + b], u02 = ucur[s0 + 64 + b];
    float u10 = ucur[s1 + b], u11 = ucur[s1 + 32 + b], u12 = ucur[s1 + 64 + b];
    float u20 = ucur[s2 + b], u21 = ucur[s2 + 32 + b], u22 = ucur[s2 + 64 + b];
    float u30 = ucur[s3 + b], u31 = ucur[s3 + 32 + b], u32 = ucur[s3 + 64 + b];
    int r0 = (int)(e0.x >> 16), r1 = (int)(e1.x >> 16);
    int r2 = (int)(e2.x >> 16), r3 = (int)(e3.x >> 16);
    float w0 = __uint_as_float(e0.y), w1 = __uint_as_float(e1.y);
    float w2 = __uint_as_float(e2.y), w3 = __uint_as_float(e3.y);
    a0 += q0[r0]*w0*u00 + q0[r1]*w1*u10 + q0[r2]*w2*u20 + q0[r3]*w3*u30;
    a1 += q1[r0]*w0*u01 + q1[r1]*w1*u11 + q1[r2]*w2*u21 + q1[r3]*w3*u31;
    a2 += q2[r0]*w0*u02 + q2[r1]*w1*u12 + q2[r2]*w2*u22 + q2[r3]*w3*u32;
  }
  if (h == 1){
    for (int i = beg + 4 * nq; i < end; ++i){
      uint2 e0 = ents[i];
      size_t s0 = (size_t)(e0.x & 0xFFFFu) * RB_;
      int r0 = (int)(e0.x >> 16);
      float w0 = __uint_as_float(e0.y);
      a0 += q0[r0] * w0 * ucur[s0 + b];
      a1 += q1[r0] * w0 * ucur[s0 + 32 + b];
      a2 += q2[r0] * w0 * ucur[s0 + 64 + b];
    }
  }
  a0 += __shfl_xor(a0, 32);
  a1 += __shfl_xor(a1, 32);
  a2 += __shfl_xor(a2, 32);
  if (h == 0){
    unxt[nb + b]      = a0;
    unxt[nb + 32 + b] = a1;
    unxt[nb + 64 + b] = a2;
    atomicAdd(&red[b], a0);
    atomicAdd(&red[32 + b], a1);
    atomicAdd(&red[64 + b], a2);
  }
  __syncthreads();
  if (tid < RB_)
    atomicAdd(&partial[(blockIdx.x & (PSLOTS - 1)) * RB_ + tid], red[tid]);
}

// ---- finalize + transpose: out[b][n] = sum_r u[n][r*32+b] / rowsum_r ----
__global__ void fintrans_kernel(const float* __restrict__ u, const float* __restrict__ partial,
                                float* __restrict__ out)
{
  __shared__ float sinv[RB_];
  __shared__ float t[B_][72];
  int tid = threadIdx.x;   // 256
  if (tid < RB_){
    float s = 0.f;
    #pragma unroll 8
    for (int k = 0; k < PSLOTS; ++k) s += partial[k * RB_ + tid];
    sinv[tid] = frcp(fmaxf(1e-20f, s));
  }
  __syncthreads();
  int n0 = blockIdx.x * 64;
  for (int i = tid; i < 64 * B_; i += 256){
    int nl = i >> 5, b = i & 31;
    int n = n0 + nl;
    float v = 0.f;
    if (n < N_){
      size_t nb = (size_t)n * RB_;
      v = u[nb + b] * sinv[b] + u[nb + 32 + b] * sinv[32 + b] + u[nb + 64 + b] * sinv[64 + b];
    }
    t[b][nl] = v;
  }
  __syncthreads();
  for (int i = tid; i < 64 * B_; i += 256){
    int b = i >> 6, nl = i & 63;
    int n = n0 + nl;
    if (n < N_) out[(size_t)b * N_ + n] = t[b][nl];
  }
}

extern "C" void kernel_launch(void* const* d_in, const int* in_sizes, int n_in,
                              void* d_out, int out_size, void* d_ws, size_t ws_size,
                              hipStream_t stream)
{
  const int*   queries = (const int*)d_in[0];
  const int*   heads   = (const int*)d_in[1];
  const int*   rels    = (const int*)d_in[2];
  const int*   t_heads = (const int*)d_in[3];
  const int*   t_tails = (const int*)d_in[4];
  const int*   edeg    = (const int*)d_in[5];
  const float* qemb    = (const float*)d_in[6];
  const float* eemb    = (const float*)d_in[7];
  const float* qWih    = (const float*)d_in[8];
  const float* qWhh    = (const float*)d_in[9];
  const float* qbih    = (const float*)d_in[10];
  const float* qbhh    = (const float*)d_in[11];
  const float* eWih    = (const float*)d_in[12];
  const float* eWhh    = (const float*)d_in[13];
  const float* ebih    = (const float*)d_in[14];
  const float* ebhh    = (const float*)d_in[15];
  const float* qlinW   = (const float*)d_in[16];
  const float* qlinb   = (const float*)d_in[17];
  const float* elinW   = (const float*)d_in[18];
  const float* elinb   = (const float*)d_in[19];
  float* out = (float*)d_out;

  char* ws = (char*)d_ws;
  size_t off = 0;
  auto alloc = [&](size_t bytes){ void* p = ws + off; off += (bytes + 255) & ~(size_t)255; return p; };
  // bigA (25.6 MB): houts during [elstm, eattn]; after eattn dead ->
  //   ents (6.4 MB, csr_fill) at +0, u2 (19.2 MB) at +6.4 MB.
  char*  bigA  = (char*)alloc((size_t)2 * N_ * H_ * 2);               // 25,600,000
  u16*   houts = (u16*)bigA;
  uint2* ents  = (uint2*)bigA;                                        // in-CSR, 6.4 MB
  float* u2    = (float*)(bigA + (size_t)2 * E_ * 8);                 // 19.2 MB
  // bigB (19.2 MB): attn (4.8 MB) during [eattn, csr_fill]; then u1; then u3.
  char*  bigB  = (char*)alloc((size_t)N_ * RB_ * 4);
  float* attn  = (float*)bigB;
  float* u1    = (float*)bigB;
  float* u3    = (float*)bigB;
  uint2* ents2      = (uint2*)alloc((size_t)2 * E_ * 8);              // out-CSR, 6.4 MB
  float* query_attn = (float*)alloc((size_t)R_ * T_ * B_ * (OPS_ + 1) * 4);
  u16*   wtile      = (u16*)  alloc((size_t)2 * 32 * 4 * 64 * 8 * 2);
  u16*   wonehot    = (u16*)  alloc((size_t)2 * 32 * 64 * 8 * 2);
  int*   counts     = (int*)  alloc((size_t)(N_ + 1) * 4);
  int*   rowptr     = (int*)  alloc((size_t)(N_ + 1) * 4);
  int*   cursor     = (int*)  alloc((size_t)(N_ + 1) * 4);
  int*   cursor2    = (int*)  alloc((size_t)(N_ + 1) * 4);
  float* sumsP      = (float*)alloc((size_t)PSLOTS * RB_ * 4);        // t2 partials only
  // total ~52 MB

  hipMemsetAsync(sumsP, 0, (size_t)PSLOTS * RB_ * 4, stream);
  hipMemsetAsync(counts, 0, (size_t)(N_ + 1) * 4, stream);

  qattn_kernel<<<R_ * B_, 256, 0, stream>>>(queries, qemb, qWih, qWhh, qbih, qbhh,
                                            qlinW, qlinb, query_attn);
  wbuild_kernel<<<(2 * 32 * 5 * 64 * 8 + 255) / 256, 256, 0, stream>>>(
      eWhh, eemb, eWih, ebih, ebhh, wtile, wonehot);
  csr_count_kernel<<<(E_ + 255) / 256, 256, 0, stream>>>(t_heads, t_tails, counts);
  csr_scan_kernel<<<1, 1024, 0, stream>>>(counts, rowptr, cursor, cursor2);
  elstm_kernel<<<(N_ + 31) / 32, 512, 0, stream>>>(edeg, wtile, wonehot, houts);
  eattn_kernel<<<(N_ + 9) / 10, 240, 0, stream>>>(houts, houts + (size_t)N_ * H_,
                                                  elinW, elinb, attn);
  // houts dead -> ents may take bigA[0:6.4M]; attn still live (read by csr_fill):
  csr_fill_kernel<<<(E_ + 255) / 256, 256, 0, stream>>>(rels, t_heads, t_tails, attn,
                                                        cursor, cursor2, ents, ents2);
  // attn dead -> u1 takes bigB
  hipMemsetAsync(u1, 0, (size_t)N_ * RB_ * 4, stream);
  t0_kernel<<<1, 128, 0, stream>>>(heads, query_attn, rowptr, ents2, u1);
  // t=1: dense self-term + sparse 2-hop pushes (replaces a full dense gather)
  u2init_kernel<<<(N_ * RB_ + 255) / 256, 256, 0, stream>>>(query_attn, u1, u2);
  t1push_kernel<<<RB_, 64, 0, stream>>>(heads, query_attn, rowptr, ents2, u1, u2);
  // t=2: dense gather (u1 dead; u3 overwrites bigB)
  gather3_kernel<<<N_ / 4, 256, 0, stream>>>(u2, u3, query_attn, 2, rowptr, ents, sumsP);
  fintrans_kernel<<<(N_ + 63) / 64, 256, 0, stream>>>(u3, sumsP, out);
}

// Round 3
// 833.787 us; speedup vs baseline: 1.3362x; 1.0590x over previous
//
#include <hip/hip_runtime.h>

#define R_ 3
#define T_ 3
#define N_ 50000
#define OPS_ 24
#define E_ 400000
#define B_ 32
#define MAXDEG_ 8
#define QD_ 128
#define ED_ 128
#define H_ 128
#define G4_ (4*H_)   /* 512 */
#define HPAD 168     /* padded LDS h-row (bf16): 128 h + 25 one-hot + pad, 336 B */
#define PSLOTS 64    /* partial row-sum slots */
#define RB_ 96       /* 3 rounds x 32 batch */

typedef unsigned short u16;
typedef __attribute__((ext_vector_type(8))) short bf16x8;     // 8 bf16 = 4 VGPRs
typedef __attribute__((ext_vector_type(8))) _Float16 f16x8;   // 8 f16  = 4 VGPRs
typedef __attribute__((ext_vector_type(4))) float f32x4;

#define BF16_ONE ((short)0x3F80)
#define LOG2E_  1.44269504f
#define LOG2E2_ 2.88539008f

__device__ __forceinline__ short f2bf(float f){
  union { float f; unsigned u; } v; v.f = f;
  unsigned r = v.u + 0x7fffu + ((v.u >> 16) & 1u);
  return (short)(r >> 16);
}
__device__ __forceinline__ float bf2f(u16 u){
  union { unsigned u; float f; } v; v.u = ((unsigned)u) << 16; return v.f;
}
__device__ __forceinline__ float frcp(float x){ return __builtin_amdgcn_rcpf(x); }
__device__ __forceinline__ float fsig(float x){ return frcp(1.0f + __expf(-x)); }
// tanh(x) = 2*sigmoid(2x) - 1
__device__ __forceinline__ float ftanh(float x){
  return __builtin_fmaf(2.0f, fsig(2.0f * x), -1.0f);
}
// 2^x via v_exp_f32 (guarded fallback keeps semantics if builtin missing)
__device__ __forceinline__ float fexp2(float x){
#if __has_builtin(__builtin_amdgcn_exp2f)
  return __builtin_amdgcn_exp2f(x);
#else
  return __expf(x * 0.6931471806f);
#endif
}

// ---------------- query BiLSTM + attention: one block per (r,b) ----------------
__global__ void qattn_kernel(const int* __restrict__ queries, const float* __restrict__ qemb,
    const float* __restrict__ qWih, const float* __restrict__ qWhh,
    const float* __restrict__ qbih, const float* __restrict__ qbhh,
    const float* __restrict__ qlinW, const float* __restrict__ qlinb,
    float* __restrict__ query_attn /* R,T,B,25 */)
{
  int r = blockIdx.x / B_;
  int b = blockIdx.x % B_;
  int tid = threadIdx.x;   // 256
  __shared__ float x[QD_];
  __shared__ float gx[G4_];
  __shared__ float h[H_], c[H_];
  __shared__ float gtmp[G4_];
  __shared__ float hh[2][T_][H_];
  __shared__ float lg[OPS_ + 1];

  int q = queries[b];
  if (tid < QD_) x[tid] = qemb[q * QD_ + tid];
  __syncthreads();

  for (int dir = 0; dir < 2; ++dir){
    const float* Wih = qWih + (size_t)(r * 2 + dir) * G4_ * QD_;
    const float* Whh = qWhh + (size_t)(r * 2 + dir) * G4_ * H_;
    const float* bih = qbih + (r * 2 + dir) * G4_;
    const float* bhh = qbhh + (r * 2 + dir) * G4_;
    for (int j = tid; j < G4_; j += 256){
      const float4* wr = (const float4*)(Wih + (size_t)j * QD_);
      float s = bih[j] + bhh[j];
      for (int k = 0; k < QD_ / 4; ++k){
        float4 wv = wr[k];
        s += wv.x * x[4*k] + wv.y * x[4*k+1] + wv.z * x[4*k+2] + wv.w * x[4*k+3];
      }
      gx[j] = s;
    }
    if (tid < H_){ h[tid] = 0.f; c[tid] = 0.f; }
    __syncthreads();
    for (int t = 0; t < T_; ++t){
      for (int j = tid; j < G4_; j += 256){
        const float4* wr = (const float4*)(Whh + (size_t)j * H_);
        float s = 0.f;
        for (int k = 0; k < H_ / 4; ++k){
          float4 wv = wr[k];
          s += wv.x * h[4*k] + wv.y * h[4*k+1] + wv.z * h[4*k+2] + wv.w * h[4*k+3];
        }
        gtmp[j] = gx[j] + s;
      }
      __syncthreads();
      if (tid < H_){
        float gi = gtmp[tid], gf = gtmp[tid + H_], gg = gtmp[tid + 2*H_], go = gtmp[tid + 3*H_];
        float cn = fsig(gf) * c[tid] + fsig(gi) * ftanh(gg);
        float hn = fsig(go) * ftanh(cn);
        c[tid] = cn; h[tid] = hn;
        hh[dir][t][tid] = hn;
      }
      __syncthreads();
    }
  }

  for (int t = 0; t < T_; ++t){
    if (tid < OPS_ + 1){
      const float* wr = qlinW + tid * (2 * H_);
      float s = qlinb[tid];
      for (int k = 0; k < H_; ++k) s += wr[k] * hh[0][t][k];
      for (int k = 0; k < H_; ++k) s += wr[H_ + k] * hh[1][T_ - 1 - t][k];
      lg[tid] = s;
    }
    __syncthreads();
    if (tid == 0){
      float m = -1e30f;
      for (int o = 0; o < OPS_ + 1; ++o) m = fmaxf(m, lg[o]);
      float sum = 0.f;
      for (int o = 0; o < OPS_ + 1; ++o){ float e = __expf(lg[o] - m); lg[o] = e; sum += e; }
      float inv = frcp(sum);
      for (int o = 0; o < OPS_ + 1; ++o) lg[o] *= inv;
    }
    __syncthreads();
    if (tid < OPS_ + 1) query_attn[((size_t)(r * T_ + t) * B_ + b) * (OPS_ + 1) + tid] = lg[tid];
    __syncthreads();
  }
}

// ---- build B-operand buffers in MFMA-fragment order (eproj folded in) ----
// Gate rows are PRE-SCALED by log2(e) (gates i,f,o) / 2*log2(e) (gate g) so the
// LSTM activation can use raw v_exp_f32 (=2^x) without per-exp ln2 muls.
__global__ void wbuild_kernel(const float* __restrict__ eWhh,
                              const float* __restrict__ eemb, const float* __restrict__ eWih,
                              const float* __restrict__ ebih, const float* __restrict__ ebhh,
                              u16* __restrict__ wtile, u16* __restrict__ wonehot)
{
  int idx = blockIdx.x * 256 + threadIdx.x;    // 2*32*5*64*8 = 163840
  if (idx >= 2 * 32 * 5 * 64 * 8) return;
  int jj = idx & 7;
  int lane = (idx >> 3) & 63;
  int kc = (idx >> 9) % 5;
  int gtile = (idx / (8 * 64 * 5)) & 31;
  int dir = idx / (8 * 64 * 5 * 32);
  int row = lane >> 4, col = lane & 15;
  int j = gtile * 16 + col;
  float sc = ((gtile >> 3) == 2) ? LOG2E2_ : LOG2E_;   // gate g rows get 2*log2e
  if (kc < 4){
    int k = kc * 32 + row * 8 + jj;
    float v = eWhh[((size_t)dir * G4_ + j) * H_ + k] * sc;
    wtile[((((size_t)dir * 32 + gtile) * 4 + kc) * 64 + lane) * 8 + jj] = (u16)f2bf(v);
  } else {
    int vdeg = row * 8 + jj;   // 0..31
    float v = 0.f;
    if (vdeg <= OPS_){
      const float4* wr = (const float4*)(eWih + (size_t)(dir * G4_ + j) * ED_);
      const float4* er = (const float4*)(eemb + (size_t)vdeg * ED_);
      float s = ebih[dir * G4_ + j] + ebhh[dir * G4_ + j];
      for (int k = 0; k < ED_ / 4; ++k){
        float4 wv = wr[k], ev = er[k];
        s += wv.x * ev.x + wv.y * ev.y + wv.z * ev.z + wv.w * ev.w;
      }
      v = s * sc;
    }
    wonehot[(((size_t)dir * 32 + gtile) * 64 + lane) * 8 + jj] = (u16)f2bf(v);
  }
}

// ------ entity BiLSTM: 512 threads / 8 waves / 32 entities per block.
// Weights stream from global (288 KB, L2-resident); per-gate bases are forced
// wave-uniform via readfirstlane -> SGPR base + shared VGPR lane offset + imm.
// Activation: pre-scaled gates -> exp2 direct; common-denominator cell form
// (5 exp2 + 2 rcp vs 5 exp + 3 rcp + 5 mul). hl double-buffered, 1 barrier/step.
// houts is stored as F16 bits (exact widening from bf16) for the MFMA eattn.
__global__ __launch_bounds__(512, 4) void elstm_kernel(
    const int* __restrict__ degs,
    const u16* __restrict__ wtile, const u16* __restrict__ wonehot,
    u16* __restrict__ houts /* 2,N,128 f16 */)
{
  int tid = threadIdx.x;
  int lane = tid & 63;
  int w = tid >> 6;          // wave 0..7
  int wu = __builtin_amdgcn_readfirstlane(w);   // provably wave-uniform
  int row = lane >> 4, col = lane & 15;
  int ebase = blockIdx.x * 32;

  __shared__ __align__(16) short hl[2][32 * HPAD];   // 2 x 10.5 KB ping-pong

  int eg0 = ebase + tid; if (eg0 >= N_) eg0 = N_ - 1;   // valid for tid<32 use

  for (int i = tid; i < 2 * 32 * HPAD; i += 512) ((short*)hl)[i] = 0;
  __syncthreads();
  if (tid < 32) hl[0][tid * HPAD + H_ + degs[(size_t)eg0 * MAXDEG_ + 0]] = BF16_ONE;
  __syncthreads();

  for (int dir = 0; dir < 2; ++dir){
    const u16* Wt  = wtile   + (size_t)dir * 32 * 4 * 64 * 8;
    const u16* Woh = wonehot + (size_t)dir * 32 * 64 * 8;
    // per-gate scalar bases (gtile = g*8 + w)
    const u16* W0 = Wt + (size_t)((0 * 8 + wu) * 4 * 64) * 8;
    const u16* W1 = Wt + (size_t)((1 * 8 + wu) * 4 * 64) * 8;
    const u16* W2 = Wt + (size_t)((2 * 8 + wu) * 4 * 64) * 8;
    const u16* W3 = Wt + (size_t)((3 * 8 + wu) * 4 * 64) * 8;
    const u16* O0 = Woh + (size_t)((0 * 8 + wu) * 64) * 8;
    const u16* O1 = Woh + (size_t)((1 * 8 + wu) * 64) * 8;
    const u16* O2 = Woh + (size_t)((2 * 8 + wu) * 64) * 8;
    const u16* O3 = Woh + (size_t)((3 * 8 + wu) * 64) * 8;
    float cst[8];
    #pragma unroll
    for (int i = 0; i < 8; ++i) cst[i] = 0.f;

    for (int t = 0; t < MAXDEG_; ++t){
      const short* hb = hl[t & 1];          // holds h_t (+ one-hot for step t)
      short*       hw = hl[(t + 1) & 1];    // receives h_{t+1}
      f32x4 acc[8];
      #pragma unroll
      for (int i = 0; i < 8; ++i) acc[i] = (f32x4){0.f, 0.f, 0.f, 0.f};

      #pragma unroll 2
      for (int kc = 0; kc < 4; ++kc){
        bf16x8 af0 = *(const bf16x8*)&hb[(col) * HPAD + kc * 32 + row * 8];
        bf16x8 af1 = *(const bf16x8*)&hb[(16 + col) * HPAD + kc * 32 + row * 8];
        int lo = (kc * 64 + lane) * 8;
        bf16x8 b0 = *(const bf16x8*)(W0 + lo);
        bf16x8 b1 = *(const bf16x8*)(W1 + lo);
        bf16x8 b2 = *(const bf16x8*)(W2 + lo);
        bf16x8 b3 = *(const bf16x8*)(W3 + lo);
        acc[0] = __builtin_amdgcn_mfma_f32_16x16x32_bf16(af0, b0, acc[0], 0, 0, 0);
        acc[1] = __builtin_amdgcn_mfma_f32_16x16x32_bf16(af1, b0, acc[1], 0, 0, 0);
        acc[2] = __builtin_amdgcn_mfma_f32_16x16x32_bf16(af0, b1, acc[2], 0, 0, 0);
        acc[3] = __builtin_amdgcn_mfma_f32_16x16x32_bf16(af1, b1, acc[3], 0, 0, 0);
        acc[4] = __builtin_amdgcn_mfma_f32_16x16x32_bf16(af0, b2, acc[4], 0, 0, 0);
        acc[5] = __builtin_amdgcn_mfma_f32_16x16x32_bf16(af1, b2, acc[5], 0, 0, 0);
        acc[6] = __builtin_amdgcn_mfma_f32_16x16x32_bf16(af0, b3, acc[6], 0, 0, 0);
        acc[7] = __builtin_amdgcn_mfma_f32_16x16x32_bf16(af1, b3, acc[7], 0, 0, 0);
      }
      {
        bf16x8 af0 = *(const bf16x8*)&hb[(col) * HPAD + H_ + row * 8];
        bf16x8 af1 = *(const bf16x8*)&hb[(16 + col) * HPAD + H_ + row * 8];
        int lo = lane * 8;
        bf16x8 b0 = *(const bf16x8*)(O0 + lo);
        bf16x8 b1 = *(const bf16x8*)(O1 + lo);
        bf16x8 b2 = *(const bf16x8*)(O2 + lo);
        bf16x8 b3 = *(const bf16x8*)(O3 + lo);
        acc[0] = __builtin_amdgcn_mfma_f32_16x16x32_bf16(af0, b0, acc[0], 0, 0, 0);
        acc[1] = __builtin_amdgcn_mfma_f32_16x16x32_bf16(af1, b0, acc[1], 0, 0, 0);
        acc[2] = __builtin_amdgcn_mfma_f32_16x16x32_bf16(af0, b1, acc[2], 0, 0, 0);
        acc[3] = __builtin_amdgcn_mfma_f32_16x16x32_bf16(af1, b1, acc[3], 0, 0, 0);
        acc[4] = __builtin_amdgcn_mfma_f32_16x16x32_bf16(af0, b2, acc[4], 0, 0, 0);
        acc[5] = __builtin_amdgcn_mfma_f32_16x16x32_bf16(af1, b2, acc[5], 0, 0, 0);
        acc[6] = __builtin_amdgcn_mfma_f32_16x16x32_bf16(af0, b3, acc[6], 0, 0, 0);
        acc[7] = __builtin_amdgcn_mfma_f32_16x16x32_bf16(af1, b3, acc[7], 0, 0, 0);
      }

      // activation (gates pre-scaled by log2e / 2log2e):
      // cn = [cst*(1+ea)(1+eb) + (1-eb)(1+ef)] / [(1+ef)(1+ea)(1+eb)]
      // hn = (1-ed) / [(1+eo)(1+ed)],  ed = 2^(-2*log2e*cn)
      #pragma unroll
      for (int mt = 0; mt < 2; ++mt){
        #pragma unroll
        for (int reg = 0; reg < 4; ++reg){
          int e = mt * 16 + row * 4 + reg;
          int j = w * 16 + col;
          float Gi = acc[0 + mt][reg];
          float Gf = acc[2 + mt][reg];
          float Gg = acc[4 + mt][reg];
          float Go = acc[6 + mt][reg];
          int ci = mt * 4 + reg;
          float ea = fexp2(-Gi);
          float ef = fexp2(-Gf);
          float eb = fexp2(-Gg);
          float eo = fexp2(-Go);
          float t1 = 1.f + ef, t2 = 1.f + ea, t3 = 1.f + eb;
          float p = t2 * t3;
          float num = __builtin_fmaf(cst[ci], p, (1.f - eb) * t1);
          float cn = num * frcp(t1 * p);
          float ed = fexp2(cn * (-LOG2E2_));
          float hn = (1.f - ed) * frcp((1.f + eo) * (1.f + ed));
          cst[ci] = cn;
          hw[e * HPAD + j] = f2bf(hn);
        }
      }
      // one-hot maintenance on the write buffer: clear the slot set 2 steps ago,
      // set the slot step t+1 will read (clear BEFORE set handles repeated degrees).
      if (tid < 32){
        const int* dr = degs + (size_t)eg0 * MAXDEG_;
        if (t >= 1)
          hw[tid * HPAD + H_ + dr[dir ? (MAXDEG_ - t) : (t - 1)]] = 0;
        if (t < MAXDEG_ - 1)
          hw[tid * HPAD + H_ + dr[dir ? (MAXDEG_ - 2 - t) : (t + 1)]] = BF16_ONE;
      }
      __syncthreads();
    }

    // MAXDEG_ even -> final h sits in hl[0]. Store as F16 (exact from bf16).
    for (int i = tid; i < 32 * H_; i += 512){
      int e = i >> 7, k = i & 127;
      int n = ebase + e;
      if (n < N_){
        _Float16 hv = (_Float16)bf2f((u16)hl[0][e * HPAD + k]);
        houts[(size_t)dir * N_ * H_ + (size_t)n * H_ + k] = *(const u16*)&hv;
      }
    }
    if (dir == 0){
      __syncthreads();
      for (int i = tid; i < 2 * 32 * HPAD; i += 512) ((short*)hl)[i] = 0;
      __syncthreads();
      if (tid < 32) hl[0][tid * HPAD + H_ + degs[(size_t)eg0 * MAXDEG_ + (MAXDEG_ - 1)]] = BF16_ONE;
      __syncthreads();
    }
  }
}

// ------------- entity attention: f16 MFMA GEMM (N x 24 = hq(N x 256) @ W^T) -------------
// One wave per 16-node group; B frags (2 op-tiles x 8 ksteps, 64 VGPR) persist per wave.
// C/D layout (verified): col = lane&15 (=op), row = (lane>>4)*4+reg (=node-in-group).
// Softmax over 24 ops = 16-lane shfl_xor reduce across the two op-tiles.
__global__ void eattn_kernel(const u16* __restrict__ hq /* f16 bits, 2 x N x 128 */,
                             const float* __restrict__ elinW, const float* __restrict__ elinb,
                             float* __restrict__ attn /* N,24 */)
{
  int tid = threadIdx.x;
  int lane = tid & 63;
  int col = lane & 15;
  int krow = lane >> 4;   // 0..3

  f16x8 Bf[2][8];
  #pragma unroll
  for (int ot = 0; ot < 2; ++ot){
    int o = ot * 16 + col;
    #pragma unroll
    for (int ks = 0; ks < 8; ++ks){
      f16x8 bv;
      if (o < OPS_){
        const float* src = elinW + (size_t)o * (2 * H_) + ks * 32 + krow * 8;
        #pragma unroll
        for (int jj = 0; jj < 8; ++jj) bv[jj] = (_Float16)src[jj];
      } else {
        #pragma unroll
        for (int jj = 0; jj < 8; ++jj) bv[jj] = (_Float16)0.f;
      }
      Bf[ot][ks] = bv;
    }
  }
  float b0 = elinb[col];
  float b1 = (col < 8) ? elinb[16 + col] : -1e30f;

  int wid = blockIdx.x * 4 + (tid >> 6);
  for (int g = wid; g < N_ / 16; g += 256 * 4){
    f16x8 Af[8];
    #pragma unroll
    for (int ks = 0; ks < 8; ++ks){
      const u16* src = hq + (size_t)(ks >> 2) * N_ * H_
                          + (size_t)(g * 16 + col) * H_ + (ks & 3) * 32 + krow * 8;
      Af[ks] = *(const f16x8*)src;
    }
    f32x4 ac0 = (f32x4){0.f, 0.f, 0.f, 0.f};
    f32x4 ac1 = (f32x4){0.f, 0.f, 0.f, 0.f};
    #pragma unroll
    for (int ks = 0; ks < 8; ++ks){
      ac0 = __builtin_amdgcn_mfma_f32_16x16x32_f16(Af[ks], Bf[0][ks], ac0, 0, 0, 0);
      ac1 = __builtin_amdgcn_mfma_f32_16x16x32_f16(Af[ks], Bf[1][ks], ac1, 0, 0, 0);
    }
    #pragma unroll
    for (int reg = 0; reg < 4; ++reg){
      int node = g * 16 + krow * 4 + reg;
      float v0 = ac0[reg] + b0;
      float v1 = (col < 8) ? (ac1[reg] + b1) : -1e30f;
      float m = fmaxf(v0, v1);
      m = fmaxf(m, __shfl_xor(m, 1));
      m = fmaxf(m, __shfl_xor(m, 2));
      m = fmaxf(m, __shfl_xor(m, 4));
      m = fmaxf(m, __shfl_xor(m, 8));
      float e0 = __expf(v0 - m);
      float e1 = (col < 8) ? __expf(v1 - m) : 0.f;
      float s = e0 + e1;
      s += __shfl_xor(s, 1);
      s += __shfl_xor(s, 2);
      s += __shfl_xor(s, 4);
      s += __shfl_xor(s, 8);
      float inv = frcp(s);
      attn[(size_t)node * OPS_ + col] = e0 * inv;
      if (col < 8) attn[(size_t)node * OPS_ + 16 + col] = e1 * inv;
    }
  }
}

// ---------------- CSR build: per-node in-edge AND out-edge lists ----------------
__global__ void csr_count_kernel(const int* __restrict__ theads, const int* __restrict__ ttails,
                                 int* __restrict__ counts)
{
  int e = blockIdx.x * 256 + threadIdx.x;
  if (e < E_){
    atomicAdd(&counts[ttails[e]], 1);
    atomicAdd(&counts[theads[e]], 1);
  }
}

__global__ void csr_scan_kernel(const int* __restrict__ counts, int* __restrict__ rowptr,
                                int* __restrict__ cursor, int* __restrict__ cursor2)
{
  __shared__ int lsum[1024];
  int t = threadIdx.x;
  const int CH = (N_ + 1023) / 1024;   // 49
  int base = t * CH;
  int s = 0;
  for (int i = 0; i < CH; ++i){
    int idx = base + i;
    if (idx < N_) s += counts[idx];
  }
  lsum[t] = s;
  __syncthreads();
  for (int o = 1; o < 1024; o <<= 1){
    int u = (t >= o) ? lsum[t - o] : 0;
    __syncthreads();
    lsum[t] += u;
    __syncthreads();
  }
  int run = lsum[t] - s;
  for (int i = 0; i < CH; ++i){
    int idx = base + i;
    if (idx < N_){
      rowptr[idx] = run;
      cursor[idx] = run;
      cursor2[idx] = run;
      run += counts[idx];
    }
  }
  if (t == 1023) rowptr[N_] = run;
}

__global__ void csr_fill_kernel(const int* __restrict__ rels, const int* __restrict__ theads,
                                const int* __restrict__ ttails, const float* __restrict__ attn,
                                int* __restrict__ cursor, int* __restrict__ cursor2,
                                uint2* __restrict__ ents, uint2* __restrict__ ents2)
{
  int e = blockIdx.x * 256 + threadIdx.x;
  if (e < E_){
    int hh = theads[e], tt = ttails[e], rel = rels[e];
    unsigned wb = __float_as_uint(attn[(size_t)hh * OPS_ + rel]);
    uint2 v1; v1.x = (unsigned)hh | ((unsigned)rel << 16);            v1.y = wb;
    uint2 v2; v2.x = (unsigned)tt | ((unsigned)(rel + OPS_/2) << 16); v2.y = wb;
    ents[atomicAdd(&cursor[tt], 1)] = v1;
    ents[atomicAdd(&cursor[hh], 1)] = v2;
    uint2 w1; w1.x = (unsigned)tt | ((unsigned)rel << 16);            w1.y = wb;
    uint2 w2; w2.x = (unsigned)hh | ((unsigned)(rel + OPS_/2) << 16); w2.y = wb;
    ents2[atomicAdd(&cursor2[hh], 1)] = w1;
    ents2[atomicAdd(&cursor2[tt], 1)] = w2;
  }
}

// ---- t=0 sparse step: u0 is one-hot(heads) -> u1 from out-edges of 32 head nodes ----
__global__ void t0_kernel(const int* __restrict__ heads, const float* __restrict__ query_attn,
                          const int* __restrict__ rowptr, const uint2* __restrict__ ents2,
                          float* __restrict__ u1 /* N x 96 */)
{
  int tid = threadIdx.x;
  if (tid >= RB_) return;
  int r = tid >> 5, b = tid & 31;
  const float* qa = query_attn + ((size_t)(r * T_ + 0) * B_ + b) * (OPS_ + 1);
  int hn = heads[b];
  int rb = r * 32 + b;
  u1[(size_t)hn * RB_ + rb] += qa[OPS_];
  int beg = rowptr[hn], end = rowptr[hn + 1];
  for (int i = beg; i < end; ++i){
    uint2 e = ents2[i];
    int dst = (int)(e.x & 0xFFFFu);
    int rl  = (int)(e.x >> 16);
    u1[(size_t)dst * RB_ + rb] += qa[rl] * __uint_as_float(e.y);
  }
}

// ---- t=1 dense self-term: u2 = qa1_24 (.) u1 (elementwise; replaces memset) ----
__global__ void u2init_kernel(const float* __restrict__ query_attn,
                              const float* __restrict__ u1, float* __restrict__ u2)
{
  __shared__ float q24[RB_];
  int tid = threadIdx.x;
  if (tid < RB_){
    int r = tid >> 5, b = tid & 31;
    q24[tid] = query_attn[((size_t)(r * T_ + 1) * B_ + b) * (OPS_ + 1) + OPS_];
  }
  __syncthreads();
  int idx = blockIdx.x * 256 + tid;
  if (idx < N_ * RB_) u2[idx] = u1[idx] * q24[idx % RB_];
}

// ---- t=1 sparse pushes: u1 nonzero only at {head} U outNbr(head) per column.
__global__ void t1push_kernel(const int* __restrict__ heads, const float* __restrict__ query_attn,
                              const int* __restrict__ rowptr, const uint2* __restrict__ ents2,
                              const float* __restrict__ u1, float* __restrict__ u2)
{
  __shared__ float qa0[OPS_ + 1], qa1[OPS_ + 1];
  int blk = blockIdx.x;   // 0..95
  int r = blk >> 5, b = blk & 31;
  int rb = r * 32 + b;
  int tid = threadIdx.x;  // 64
  if (tid < OPS_ + 1){
    qa0[tid] = query_attn[((size_t)(r * T_ + 0) * B_ + b) * (OPS_ + 1) + tid];
    qa1[tid] = query_attn[((size_t)(r * T_ + 1) * B_ + b) * (OPS_ + 1) + tid];
  }
  __syncthreads();
  int hd = heads[b];
  int beg = rowptr[hd], end = rowptr[hd + 1];
  float q024 = qa0[OPS_];
  for (int i = beg + tid; i < end; i += 64){
    uint2 e1 = ents2[i];
    int s  = (int)(e1.x & 0xFFFFu);
    int r1 = (int)(e1.x >> 16);
    float w1 = __uint_as_float(e1.y);
    atomicAdd(&u2[(size_t)s * RB_ + rb], qa1[r1] * w1 * q024);
    float v1 = qa0[r1] * w1;      // this path's share of u1[s]
    int b2 = rowptr[s], e2e = rowptr[s + 1];
    for (int jj = b2; jj < e2e; ++jj){
      uint2 e2 = ents2[jj];
      int d2 = (int)(e2.x & 0xFFFFu);
      int r2 = (int)(e2.x >> 16);
      atomicAdd(&u2[(size_t)d2 * RB_ + rb], qa1[r2] * __uint_as_float(e2.y) * v1);
    }
  }
}

// ---- batched dense gather (t=2): ONE WAVE per node, halves split 4-edge chunks ----
__global__ __launch_bounds__(256) void gather3_kernel(
    const float* __restrict__ ucur, float* __restrict__ unxt,
    const float* __restrict__ query_attn, int t,
    const int* __restrict__ rowptr, const uint2* __restrict__ ents,
    float* __restrict__ partial /* PSLOTS x 96 */)
{
  __shared__ float qas[3 * B_ * (OPS_ + 1)];  // [r][b][o]
  __shared__ float red[RB_];
  int tid = threadIdx.x;
  for (int i = tid; i < 3 * B_ * (OPS_ + 1); i += 256){
    int r = i / (B_ * (OPS_ + 1));
    int rem = i - r * (B_ * (OPS_ + 1));
    qas[i] = query_attn[(size_t)(r * T_ + t) * B_ * (OPS_ + 1) + rem];
  }
  if (tid < RB_) red[tid] = 0.f;
  __syncthreads();
  int b  = tid & 31;
  int h  = (tid >> 5) & 1;              // half within wave
  int n = blockIdx.x * 4 + (tid >> 6);  // one wave per node; grid*4 == N_
  const float* q0 = &qas[0 * 800 + b * (OPS_ + 1)];
  const float* q1 = &qas[1 * 800 + b * (OPS_ + 1)];
  const float* q2 = &qas[2 * 800 + b * (OPS_ + 1)];
  size_t nb = (size_t)n * RB_;
  float a0 = 0.f, a1 = 0.f, a2 = 0.f;
  if (h == 0){
    a0 = ucur[nb + b]      * q0[OPS_];
    a1 = ucur[nb + 32 + b] * q1[OPS_];
    a2 = ucur[nb + 64 + b] * q2[OPS_];
  }
  int beg = rowptr[n], end = rowptr[n + 1];
  int cnt = end - beg;
  int nq = cnt >> 2;                 // full 4-edge chunks
  for (int c = h; c < nq; c += 2){
    int i0 = beg + 4 * c;
    uint2 e0 = ents[i0 + 0];
    uint2 e1 = ents[i0 + 1];
    uint2 e2 = ents[i0 + 2];
    uint2 e3 = ents[i0 + 3];
    size_t s0 = (size_t)(e0.x & 0xFFFFu) * RB_;
    size_t s1 = (size_t)(e1.x & 0xFFFFu) * RB_;
    size_t s2 = (size_t)(e2.x & 0xFFFFu) * RB_;
    size_t s3 = (size_t)(e3.x & 0xFFFFu) * RB_;
    float u00 = ucur[s0 + b], u01 = ucur[s0 + 32 + b], u02 = ucur[s0 + 64 + b];
    float u10 = ucur[s1 + b], u11 = ucur[s1 + 32 + b], u12 = ucur[s1 + 64 + b];
    float u20 = ucur[s2 + b], u21 = ucur[s2 + 32 + b], u22 = ucur[s2 + 64 + b];
    float u30 = ucur[s3 + b], u31 = ucur[s3 + 32 + b], u32 = ucur[s3 + 64 + b];
    int r0 = (int)(e0.x >> 16), r1 = (int)(e1.x >> 16);
    int r2 = (int)(e2.x >> 16), r3 = (int)(e3.x >> 16);
    float w0 = __uint_as_float(e0.y), w1 = __uint_as_float(e1.y);
    float w2 = __uint_as_float(e2.y), w3 = __uint_as_float(e3.y);
    a0 += q0[r0]*w0*u00 + q0[r1]*w1*u10 + q0[r2]*w2*u20 + q0[r3]*w3*u30;
    a1 += q1[r0]*w0*u01 + q1[r1]*w1*u11 + q1[r2]*w2*u21 + q1[r3]*w3*u31;
    a2 += q2[r0]*w0*u02 + q2[r1]*w1*u12 + q2[r2]*w2*u22 + q2[r3]*w3*u32;
  }
  if (h == 1){
    for (int i = beg + 4 * nq; i < end; ++i){
      uint2 e0 = ents[i];
      size_t s0 = (size_t)(e0.x & 0xFFFFu) * RB_;
      int r0 = (int)(e0.x >> 16);
      float w0 = __uint_as_float(e0.y);
      a0 += q0[r0] * w0 * ucur[s0 + b];
      a1 += q1[r0] * w0 * ucur[s0 + 32 + b];
      a2 += q2[r0] * w0 * ucur[s0 + 64 + b];
    }
  }
  a0 += __shfl_xor(a0, 32);
  a1 += __shfl_xor(a1, 32);
  a2 += __shfl_xor(a2, 32);
  if (h == 0){
    unxt[nb + b]      = a0;
    unxt[nb + 32 + b] = a1;
    unxt[nb + 64 + b] = a2;
    atomicAdd(&red[b], a0);
    atomicAdd(&red[32 + b], a1);
    atomicAdd(&red[64 + b], a2);
  }
  __syncthreads();
  if (tid < RB_)
    atomicAdd(&partial[(blockIdx.x & (PSLOTS - 1)) * RB_ + tid], red[tid]);
}

// ---- finalize + transpose: out[b][n] = sum_r u[n][r*32+b] / rowsum_r ----
__global__ void fintrans_kernel(const float* __restrict__ u, const float* __restrict__ partial,
                                float* __restrict__ out)
{
  __shared__ float sinv[RB_];
  __shared__ float t[B_][72];
  int tid = threadIdx.x;   // 256
  if (tid < RB_){
    float s = 0.f;
    #pragma unroll 8
    for (int k = 0; k < PSLOTS; ++k) s += partial[k * RB_ + tid];
    sinv[tid] = frcp(fmaxf(1e-20f, s));
  }
  __syncthreads();
  int n0 = blockIdx.x * 64;
  for (int i = tid; i < 64 * B_; i += 256){
    int nl = i >> 5, b = i & 31;
    int n = n0 + nl;
    float v = 0.f;
    if (n < N_){
      size_t nb = (size_t)n * RB_;
      v = u[nb + b] * sinv[b] + u[nb + 32 + b] * sinv[32 + b] + u[nb + 64 + b] * sinv[64 + b];
    }
    t[b][nl] = v;
  }
  __syncthreads();
  for (int i = tid; i < 64 * B_; i += 256){
    int b = i >> 6, nl = i & 63;
    int n = n0 + nl;
    if (n < N_) out[(size_t)b * N_ + n] = t[b][nl];
  }
}

extern "C" void kernel_launch(void* const* d_in, const int* in_sizes, int n_in,
                              void* d_out, int out_size, void* d_ws, size_t ws_size,
                              hipStream_t stream)
{
  const int*   queries = (const int*)d_in[0];
  const int*   heads   = (const int*)d_in[1];
  const int*   rels    = (const int*)d_in[2];
  const int*   t_heads = (const int*)d_in[3];
  const int*   t_tails = (const int*)d_in[4];
  const int*   edeg    = (const int*)d_in[5];
  const float* qemb    = (const float*)d_in[6];
  const float* eemb    = (const float*)d_in[7];
  const float* qWih    = (const float*)d_in[8];
  const float* qWhh    = (const float*)d_in[9];
  const float* qbih    = (const float*)d_in[10];
  const float* qbhh    = (const float*)d_in[11];
  const float* eWih    = (const float*)d_in[12];
  const float* eWhh    = (const float*)d_in[13];
  const float* ebih    = (const float*)d_in[14];
  const float* ebhh    = (const float*)d_in[15];
  const float* qlinW   = (const float*)d_in[16];
  const float* qlinb   = (const float*)d_in[17];
  const float* elinW   = (const float*)d_in[18];
  const float* elinb   = (const float*)d_in[19];
  float* out = (float*)d_out;

  char* ws = (char*)d_ws;
  size_t off = 0;
  auto alloc = [&](size_t bytes){ void* p = ws + off; off += (bytes + 255) & ~(size_t)255; return p; };
  // bigA (25.6 MB): houts during [elstm, eattn]; after eattn dead ->
  //   ents (6.4 MB, csr_fill) at +0, u2 (19.2 MB) at +6.4 MB.
  char*  bigA  = (char*)alloc((size_t)2 * N_ * H_ * 2);               // 25,600,000
  u16*   houts = (u16*)bigA;                                          // f16 bits
  uint2* ents  = (uint2*)bigA;                                        // in-CSR, 6.4 MB
  float* u2    = (float*)(bigA + (size_t)2 * E_ * 8);                 // 19.2 MB
  // bigB (19.2 MB): attn (4.8 MB) during [eattn, csr_fill]; then u1; then u3.
  char*  bigB  = (char*)alloc((size_t)N_ * RB_ * 4);
  float* attn  = (float*)bigB;
  float* u1    = (float*)bigB;
  float* u3    = (float*)bigB;
  uint2* ents2      = (uint2*)alloc((size_t)2 * E_ * 8);              // out-CSR, 6.4 MB
  float* query_attn = (float*)alloc((size_t)R_ * T_ * B_ * (OPS_ + 1) * 4);
  u16*   wtile      = (u16*)  alloc((size_t)2 * 32 * 4 * 64 * 8 * 2);
  u16*   wonehot    = (u16*)  alloc((size_t)2 * 32 * 64 * 8 * 2);
  int*   counts     = (int*)  alloc((size_t)(N_ + 1) * 4);
  int*   rowptr     = (int*)  alloc((size_t)(N_ + 1) * 4);
  int*   cursor     = (int*)  alloc((size_t)(N_ + 1) * 4);
  int*   cursor2    = (int*)  alloc((size_t)(N_ + 1) * 4);
  float* sumsP      = (float*)alloc((size_t)PSLOTS * RB_ * 4);        // t2 partials only
  // total ~52 MB

  hipMemsetAsync(sumsP, 0, (size_t)PSLOTS * RB_ * 4, stream);
  hipMemsetAsync(counts, 0, (size_t)(N_ + 1) * 4, stream);

  qattn_kernel<<<R_ * B_, 256, 0, stream>>>(queries, qemb, qWih, qWhh, qbih, qbhh,
                                            qlinW, qlinb, query_attn);
  wbuild_kernel<<<(2 * 32 * 5 * 64 * 8 + 255) / 256, 256, 0, stream>>>(
      eWhh, eemb, eWih, ebih, ebhh, wtile, wonehot);
  csr_count_kernel<<<(E_ + 255) / 256, 256, 0, stream>>>(t_heads, t_tails, counts);
  csr_scan_kernel<<<1, 1024, 0, stream>>>(counts, rowptr, cursor, cursor2);
  elstm_kernel<<<(N_ + 31) / 32, 512, 0, stream>>>(edeg, wtile, wonehot, houts);
  eattn_kernel<<<256, 256, 0, stream>>>(houts, elinW, elinb, attn);
  // houts dead -> ents may take bigA[0:6.4M]; attn still live (read by csr_fill):
  csr_fill_kernel<<<(E_ + 255) / 256, 256, 0, stream>>>(rels, t_heads, t_tails, attn,
                                                        cursor, cursor2, ents, ents2);
  // attn dead -> u1 takes bigB
  hipMemsetAsync(u1, 0, (size_t)N_ * RB_ * 4, stream);
  t0_kernel<<<1, 128, 0, stream>>>(heads, query_attn, rowptr, ents2, u1);
  // t=1: dense self-term + sparse 2-hop pushes (replaces a full dense gather)
  u2init_kernel<<<(N_ * RB_ + 255) / 256, 256, 0, stream>>>(query_attn, u1, u2);
  t1push_kernel<<<RB_, 64, 0, stream>>>(heads, query_attn, rowptr, ents2, u1, u2);
  // t=2: dense gather (u1 dead; u3 overwrites bigB)
  gather3_kernel<<<N_ / 4, 256, 0, stream>>>(u2, u3, query_attn, 2, rowptr, ents, sumsP);
  fintrans_kernel<<<(N_ + 63) / 64, 256, 0, stream>>>(u3, sumsP, out);
}